// Round 1
// baseline (692.883 us; speedup 1.0000x reference)
//
#include <hip/hip_runtime.h>

#define N_NODES 100000
#define N_EDGES 1000000

// ws layout (float offsets):
//   cnt  : [0,        102400)
//   agg1 : [102400,   6502400)     N*64
//   agg2 : [6502400,  12902400)    N*64
//   h    : [12902400, 25702400)    N*128
//   p    : [25702400, 32102400)    N*64   (h @ W2l, pre-aggregation)
//   q    : [32102400, 38502400)    N*64   (h @ W2r + b2)
// total 38,502,400 floats = 154,009,600 bytes

__global__ __launch_bounds__(256) void zero_kernel(float4* __restrict__ ws, int n4) {
    int i = blockIdx.x * blockDim.x + threadIdx.x;
    if (i < n4) ws[i] = make_float4(0.f, 0.f, 0.f, 0.f);
}

// One wave (64 lanes) per edge: lane f handles feature f.
// Reads src row coalesced (256B), atomicAdds into dst row.
__global__ __launch_bounds__(256) void scatter_kernel(
        const float* __restrict__ feat, const int* __restrict__ ei,
        float* __restrict__ agg, float* __restrict__ cnt, int do_cnt) {
    int tid = blockIdx.x * blockDim.x + threadIdx.x;
    int e = tid >> 6;
    int f = tid & 63;
    if (e >= N_EDGES) return;
    int s = ei[e];
    int d = ei[N_EDGES + e];
    atomicAdd(&agg[d * 64 + f], feat[s * 64 + f]);
    if (do_cnt && f == 0) atomicAdd(&cnt[d], 1.0f);
}

// Layer 1: h = relu( (agg1/cnt) @ W1l + x @ W1r + b1 )
// GEMM view: [N,128] = A[N,128] @ B[128,128],  A = [mean | x], B = [W1l ; W1r]
// Block: 64 rows x 128 cols, 256 threads, per-thread 4x8 micro-tile.
__global__ __launch_bounds__(256) void l1_kernel(
        const float* __restrict__ x, const float* __restrict__ agg1,
        const float* __restrict__ cnt,
        const float* __restrict__ W1l, const float* __restrict__ W1r,
        const float* __restrict__ b1, float* __restrict__ h) {
    __shared__ float At[32 * 68];    // A^T chunk: [k=32][row=64 pad 68]
    __shared__ float Bs[32 * 128];   // B chunk:   [k=32][j=128]

    const int t = threadIdx.x;
    const int ty = t >> 4;           // 0..15 -> row group
    const int tx = t & 15;           // 0..15 -> col group
    const int rowBase = blockIdx.x * 64;

    float acc[4][8];
#pragma unroll
    for (int i = 0; i < 4; ++i)
#pragma unroll
        for (int j = 0; j < 8; ++j) acc[i][j] = 0.f;

    // A staging mapping: each thread loads 8 consecutive k for one row
    const int arow = t >> 2;             // 0..63
    const int akq  = (t & 3) * 8;        // 0,8,16,24
    const int grow = rowBase + arow;
    const bool avalid = grow < N_NODES;
    float inv = 0.f;
    if (avalid) inv = 1.0f / fmaxf(cnt[grow], 1.0f);

    // B staging mapping: each thread loads 16 consecutive j for one k
    const int bk = t >> 3;               // 0..31
    const int bj = (t & 7) * 16;         // 0..112

    for (int kt = 0; kt < 4; ++kt) {
        // ---- stage A^T ----
        {
            float4 v0 = make_float4(0.f,0.f,0.f,0.f);
            float4 v1 = make_float4(0.f,0.f,0.f,0.f);
            if (avalid) {
                const float* Asrc = (kt < 2)
                    ? (agg1 + grow * 64 + kt * 32 + akq)
                    : (x    + grow * 64 + (kt - 2) * 32 + akq);
                v0 = *(const float4*)Asrc;
                v1 = *(const float4*)(Asrc + 4);
                if (kt < 2) {
                    v0.x *= inv; v0.y *= inv; v0.z *= inv; v0.w *= inv;
                    v1.x *= inv; v1.y *= inv; v1.z *= inv; v1.w *= inv;
                }
            }
            At[(akq + 0) * 68 + arow] = v0.x;
            At[(akq + 1) * 68 + arow] = v0.y;
            At[(akq + 2) * 68 + arow] = v0.z;
            At[(akq + 3) * 68 + arow] = v0.w;
            At[(akq + 4) * 68 + arow] = v1.x;
            At[(akq + 5) * 68 + arow] = v1.y;
            At[(akq + 6) * 68 + arow] = v1.z;
            At[(akq + 7) * 68 + arow] = v1.w;
        }
        // ---- stage B ----
        {
            const int kg = kt * 32 + bk;
            const float* Bsrc = (kg < 64)
                ? (W1l + kg * 128 + bj)
                : (W1r + (kg - 64) * 128 + bj);
            float4 u0 = *(const float4*)(Bsrc + 0);
            float4 u1 = *(const float4*)(Bsrc + 4);
            float4 u2 = *(const float4*)(Bsrc + 8);
            float4 u3 = *(const float4*)(Bsrc + 12);
            *(float4*)&Bs[bk * 128 + bj + 0]  = u0;
            *(float4*)&Bs[bk * 128 + bj + 4]  = u1;
            *(float4*)&Bs[bk * 128 + bj + 8]  = u2;
            *(float4*)&Bs[bk * 128 + bj + 12] = u3;
        }
        __syncthreads();
#pragma unroll
        for (int k = 0; k < 32; ++k) {
            float4 a  = *(const float4*)&At[k * 68 + ty * 4];
            float4 b0 = *(const float4*)&Bs[k * 128 + tx * 8];
            float4 b1v = *(const float4*)&Bs[k * 128 + tx * 8 + 4];
            float av[4] = {a.x, a.y, a.z, a.w};
            float bv[8] = {b0.x, b0.y, b0.z, b0.w, b1v.x, b1v.y, b1v.z, b1v.w};
#pragma unroll
            for (int i = 0; i < 4; ++i)
#pragma unroll
                for (int j = 0; j < 8; ++j) acc[i][j] += av[i] * bv[j];
        }
        __syncthreads();
    }

    // ---- epilogue: bias + relu ----
    const int c0 = tx * 8;
    float4 bb0 = *(const float4*)&b1[c0];
    float4 bb1 = *(const float4*)&b1[c0 + 4];
    float bias[8] = {bb0.x, bb0.y, bb0.z, bb0.w, bb1.x, bb1.y, bb1.z, bb1.w};
#pragma unroll
    for (int i = 0; i < 4; ++i) {
        int rg = rowBase + ty * 4 + i;
        if (rg < N_NODES) {
            float o[8];
#pragma unroll
            for (int j = 0; j < 8; ++j) o[j] = fmaxf(acc[i][j] + bias[j], 0.f);
            *(float4*)&h[rg * 128 + c0 + 0] = make_float4(o[0], o[1], o[2], o[3]);
            *(float4*)&h[rg * 128 + c0 + 4] = make_float4(o[4], o[5], o[6], o[7]);
        }
    }
}

// Layer 2 matmuls: p = h @ W2l  (to be aggregated), q = h @ W2r + b2
// GEMM view: [N,128] = h[N,128] @ [W2l | W2r][128,128]
__global__ __launch_bounds__(256) void l2_kernel(
        const float* __restrict__ h,
        const float* __restrict__ W2l, const float* __restrict__ W2r,
        const float* __restrict__ b2,
        float* __restrict__ p, float* __restrict__ q) {
    __shared__ float At[32 * 68];
    __shared__ float Bs[32 * 128];

    const int t = threadIdx.x;
    const int ty = t >> 4;
    const int tx = t & 15;
    const int rowBase = blockIdx.x * 64;

    float acc[4][8];
#pragma unroll
    for (int i = 0; i < 4; ++i)
#pragma unroll
        for (int j = 0; j < 8; ++j) acc[i][j] = 0.f;

    const int arow = t >> 2;
    const int akq  = (t & 3) * 8;
    const int grow = rowBase + arow;
    const bool avalid = grow < N_NODES;

    const int bk = t >> 3;
    const int bj = (t & 7) * 16;
    const float* BsrcBase = (bj < 64) ? W2l : W2r;
    const int bjj = bj & 63;

    for (int kt = 0; kt < 4; ++kt) {
        {
            float4 v0 = make_float4(0.f,0.f,0.f,0.f);
            float4 v1 = make_float4(0.f,0.f,0.f,0.f);
            if (avalid) {
                const float* Asrc = h + grow * 128 + kt * 32 + akq;
                v0 = *(const float4*)Asrc;
                v1 = *(const float4*)(Asrc + 4);
            }
            At[(akq + 0) * 68 + arow] = v0.x;
            At[(akq + 1) * 68 + arow] = v0.y;
            At[(akq + 2) * 68 + arow] = v0.z;
            At[(akq + 3) * 68 + arow] = v0.w;
            At[(akq + 4) * 68 + arow] = v1.x;
            At[(akq + 5) * 68 + arow] = v1.y;
            At[(akq + 6) * 68 + arow] = v1.z;
            At[(akq + 7) * 68 + arow] = v1.w;
        }
        {
            const int kg = kt * 32 + bk;
            const float* Bsrc = BsrcBase + kg * 64 + bjj;
            float4 u0 = *(const float4*)(Bsrc + 0);
            float4 u1 = *(const float4*)(Bsrc + 4);
            float4 u2 = *(const float4*)(Bsrc + 8);
            float4 u3 = *(const float4*)(Bsrc + 12);
            *(float4*)&Bs[bk * 128 + bj + 0]  = u0;
            *(float4*)&Bs[bk * 128 + bj + 4]  = u1;
            *(float4*)&Bs[bk * 128 + bj + 8]  = u2;
            *(float4*)&Bs[bk * 128 + bj + 12] = u3;
        }
        __syncthreads();
#pragma unroll
        for (int k = 0; k < 32; ++k) {
            float4 a  = *(const float4*)&At[k * 68 + ty * 4];
            float4 b0 = *(const float4*)&Bs[k * 128 + tx * 8];
            float4 b1v = *(const float4*)&Bs[k * 128 + tx * 8 + 4];
            float av[4] = {a.x, a.y, a.z, a.w};
            float bv[8] = {b0.x, b0.y, b0.z, b0.w, b1v.x, b1v.y, b1v.z, b1v.w};
#pragma unroll
            for (int i = 0; i < 4; ++i)
#pragma unroll
                for (int j = 0; j < 8; ++j) acc[i][j] += av[i] * bv[j];
        }
        __syncthreads();
    }

    const int c0 = tx * 8;
    if (tx < 8) {
        // p = h @ W2l (no bias)
#pragma unroll
        for (int i = 0; i < 4; ++i) {
            int rg = rowBase + ty * 4 + i;
            if (rg < N_NODES) {
                *(float4*)&p[rg * 64 + c0 + 0] =
                    make_float4(acc[i][0], acc[i][1], acc[i][2], acc[i][3]);
                *(float4*)&p[rg * 64 + c0 + 4] =
                    make_float4(acc[i][4], acc[i][5], acc[i][6], acc[i][7]);
            }
        }
    } else {
        const int cq = c0 - 64;
        float4 bb0 = *(const float4*)&b2[cq];
        float4 bb1 = *(const float4*)&b2[cq + 4];
        float bias[8] = {bb0.x, bb0.y, bb0.z, bb0.w, bb1.x, bb1.y, bb1.z, bb1.w};
#pragma unroll
        for (int i = 0; i < 4; ++i) {
            int rg = rowBase + ty * 4 + i;
            if (rg < N_NODES) {
                *(float4*)&q[rg * 64 + cq + 0] =
                    make_float4(acc[i][0] + bias[0], acc[i][1] + bias[1],
                                acc[i][2] + bias[2], acc[i][3] + bias[3]);
                *(float4*)&q[rg * 64 + cq + 4] =
                    make_float4(acc[i][4] + bias[4], acc[i][5] + bias[5],
                                acc[i][6] + bias[6], acc[i][7] + bias[7]);
            }
        }
    }
}

// out = agg2/cnt + q
__global__ __launch_bounds__(256) void final_kernel(
        const float* __restrict__ agg2, const float* __restrict__ cnt,
        const float* __restrict__ q, float* __restrict__ out) {
    int i = blockIdx.x * blockDim.x + threadIdx.x;   // over N*16 float4 groups
    if (i >= N_NODES * 16) return;
    int node = i >> 4;
    int c = (i & 15) * 4;
    float inv = 1.0f / fmaxf(cnt[node], 1.0f);
    float4 a = *(const float4*)&agg2[node * 64 + c];
    float4 qq = *(const float4*)&q[node * 64 + c];
    *(float4*)&out[node * 64 + c] =
        make_float4(a.x * inv + qq.x, a.y * inv + qq.y,
                    a.z * inv + qq.z, a.w * inv + qq.w);
}

extern "C" void kernel_launch(void* const* d_in, const int* in_sizes, int n_in,
                              void* d_out, int out_size, void* d_ws, size_t ws_size,
                              hipStream_t stream) {
    const float* x   = (const float*)d_in[0];
    const float* W1l = (const float*)d_in[1];
    const float* W1r = (const float*)d_in[2];
    const float* b1  = (const float*)d_in[3];
    const float* W2l = (const float*)d_in[4];
    const float* W2r = (const float*)d_in[5];
    const float* b2  = (const float*)d_in[6];
    const int*   ei  = (const int*)d_in[7];

    float* ws   = (float*)d_ws;
    float* cnt  = ws;
    float* agg1 = ws + 102400;
    float* agg2 = ws + 6502400;
    float* h    = ws + 12902400;
    float* p    = ws + 25702400;
    float* q    = ws + 32102400;
    float* out  = (float*)d_out;

    // zero cnt + agg1 + agg2 (contiguous prefix: 12,902,400 floats)
    {
        int n4 = 12902400 / 4;
        zero_kernel<<<(n4 + 255) / 256, 256, 0, stream>>>((float4*)ws, n4);
    }
    // layer-1 aggregation (+ degree counts)
    scatter_kernel<<<(N_EDGES * 64) / 256, 256, 0, stream>>>(x, ei, agg1, cnt, 1);
    // h = relu(mean @ W1l + x @ W1r + b1)
    l1_kernel<<<(N_NODES + 63) / 64, 256, 0, stream>>>(x, agg1, cnt, W1l, W1r, b1, h);
    // p = h @ W2l ; q = h @ W2r + b2
    l2_kernel<<<(N_NODES + 63) / 64, 256, 0, stream>>>(h, W2l, W2r, b2, p, q);
    // layer-2 aggregation of p
    scatter_kernel<<<(N_EDGES * 64) / 256, 256, 0, stream>>>(p, ei, agg2, cnt, 0);
    // out = agg2/cnt + q
    final_kernel<<<(N_NODES * 16 + 255) / 256, 256, 0, stream>>>(agg2, cnt, q, out);
}

// Round 2
// 357.478 us; speedup vs baseline: 1.9383x; 1.9383x over previous
//
#include <hip/hip_runtime.h>

#define N_NODES 100000
#define N_EDGES 1000000
#define DEG_CAP 64
#define OVF_CAP 4096

// ws layout (element offsets, 4B units):
//   counts : int  [0,        102400)
//   slots  : int  [102400,   6502400)    N*64 padded adjacency (src ids)
//   ovfc   : int  [6502400]              overflow count
//   ovf    : int  [6502464,  6510656)    overflow (src,dst) pairs
//   A      : f32  [6512640,  12912640)   agg1, later reused as p
//   H      : f32  [12912640, 25712640)   h (N*128); first 6.4M reused as agg2
//   q      : f32  [25712640, 32112640)
// total 32,112,640 elems = 128.5 MB  (round-1 used 154 MB, so it fits)

__global__ __launch_bounds__(256) void init_kernel(int* __restrict__ counts,
                                                   int* __restrict__ ovfc) {
    int i = blockIdx.x * blockDim.x + threadIdx.x;
    if (i < N_NODES) counts[i] = 0;
    if (i == 0) *ovfc = 0;
}

// One thread per edge: histogram degree + write src into padded slot.
__global__ __launch_bounds__(256) void hist_bucket_kernel(
        const int* __restrict__ ei, int* __restrict__ counts,
        int* __restrict__ slots, int* __restrict__ ovfc, int* __restrict__ ovf) {
    int e = blockIdx.x * blockDim.x + threadIdx.x;
    if (e >= N_EDGES) return;
    int s = ei[e];
    int d = ei[N_EDGES + e];
    int pos = atomicAdd(&counts[d], 1);
    if (pos < DEG_CAP) {
        slots[d * DEG_CAP + pos] = s;
    } else {
        int o = atomicAdd(ovfc, 1);
        if (o < OVF_CAP) { ovf[o * 2] = s; ovf[o * 2 + 1] = d; }
    }
}

// One wave per node, lane = feature. Neighbor ids preloaded (1 coalesced
// 256B read), broadcast by __shfl; feature rows are 256B coalesced reads.
// Writes RAW SUM (division by count happens in the consumer).
__global__ __launch_bounds__(256) void gather_kernel(
        const float* __restrict__ feat, const int* __restrict__ counts,
        const int* __restrict__ slots, float* __restrict__ agg) {
    int wid = blockIdx.x * 4 + (threadIdx.x >> 6);
    int f = threadIdx.x & 63;
    if (wid >= N_NODES) return;
    int deg = counts[wid];
    int dcap = min(deg, DEG_CAP);
    int ids = slots[wid * DEG_CAP + f];   // lane j holds neighbor j (j<dcap valid)
    float sum = 0.f;
    int j = 0;
    for (; j + 4 <= dcap; j += 4) {
        int s0 = __shfl(ids, j + 0);
        int s1 = __shfl(ids, j + 1);
        int s2 = __shfl(ids, j + 2);
        int s3 = __shfl(ids, j + 3);
        float v0 = feat[s0 * 64 + f];
        float v1 = feat[s1 * 64 + f];
        float v2 = feat[s2 * 64 + f];
        float v3 = feat[s3 * 64 + f];
        sum += v0 + v1 + v2 + v3;
    }
    for (; j < dcap; ++j) {
        int s = __shfl(ids, j);
        sum += feat[s * 64 + f];
    }
    agg[wid * 64 + f] = sum;
}

// Handles the (normally empty) deg>64 overflow edges with atomics.
__global__ __launch_bounds__(64) void ovf_scatter_kernel(
        const float* __restrict__ feat, const int* __restrict__ ovf,
        const int* __restrict__ ovfc, float* __restrict__ agg) {
    int n = *ovfc;
    if (n > OVF_CAP) n = OVF_CAP;
    for (int idx = blockIdx.x; idx < n; idx += gridDim.x) {
        int s = ovf[idx * 2];
        int d = ovf[idx * 2 + 1];
        atomicAdd(&agg[d * 64 + threadIdx.x], feat[s * 64 + threadIdx.x]);
    }
}

// Layer 1: h = relu( (agg1/cnt) @ W1l + x @ W1r + b1 )
// GEMM view: [N,128] = A[N,128] @ B[128,128],  A = [mean | x], B = [W1l ; W1r]
__global__ __launch_bounds__(256) void l1_kernel(
        const float* __restrict__ x, const float* __restrict__ agg1,
        const int* __restrict__ counts,
        const float* __restrict__ W1l, const float* __restrict__ W1r,
        const float* __restrict__ b1, float* __restrict__ h) {
    __shared__ float At[32 * 68];    // A^T chunk: [k=32][row=64 pad 68]
    __shared__ float Bs[32 * 128];   // B chunk:   [k=32][j=128]

    const int t = threadIdx.x;
    const int ty = t >> 4;
    const int tx = t & 15;
    const int rowBase = blockIdx.x * 64;

    float acc[4][8];
#pragma unroll
    for (int i = 0; i < 4; ++i)
#pragma unroll
        for (int j = 0; j < 8; ++j) acc[i][j] = 0.f;

    const int arow = t >> 2;
    const int akq  = (t & 3) * 8;
    const int grow = rowBase + arow;
    const bool avalid = grow < N_NODES;
    float inv = 0.f;
    if (avalid) inv = 1.0f / fmaxf((float)counts[grow], 1.0f);

    const int bk = t >> 3;
    const int bj = (t & 7) * 16;

    for (int kt = 0; kt < 4; ++kt) {
        {
            float4 v0 = make_float4(0.f,0.f,0.f,0.f);
            float4 v1 = make_float4(0.f,0.f,0.f,0.f);
            if (avalid) {
                const float* Asrc = (kt < 2)
                    ? (agg1 + grow * 64 + kt * 32 + akq)
                    : (x    + grow * 64 + (kt - 2) * 32 + akq);
                v0 = *(const float4*)Asrc;
                v1 = *(const float4*)(Asrc + 4);
                if (kt < 2) {
                    v0.x *= inv; v0.y *= inv; v0.z *= inv; v0.w *= inv;
                    v1.x *= inv; v1.y *= inv; v1.z *= inv; v1.w *= inv;
                }
            }
            At[(akq + 0) * 68 + arow] = v0.x;
            At[(akq + 1) * 68 + arow] = v0.y;
            At[(akq + 2) * 68 + arow] = v0.z;
            At[(akq + 3) * 68 + arow] = v0.w;
            At[(akq + 4) * 68 + arow] = v1.x;
            At[(akq + 5) * 68 + arow] = v1.y;
            At[(akq + 6) * 68 + arow] = v1.z;
            At[(akq + 7) * 68 + arow] = v1.w;
        }
        {
            const int kg = kt * 32 + bk;
            const float* Bsrc = (kg < 64)
                ? (W1l + kg * 128 + bj)
                : (W1r + (kg - 64) * 128 + bj);
            float4 u0 = *(const float4*)(Bsrc + 0);
            float4 u1 = *(const float4*)(Bsrc + 4);
            float4 u2 = *(const float4*)(Bsrc + 8);
            float4 u3 = *(const float4*)(Bsrc + 12);
            *(float4*)&Bs[bk * 128 + bj + 0]  = u0;
            *(float4*)&Bs[bk * 128 + bj + 4]  = u1;
            *(float4*)&Bs[bk * 128 + bj + 8]  = u2;
            *(float4*)&Bs[bk * 128 + bj + 12] = u3;
        }
        __syncthreads();
#pragma unroll
        for (int k = 0; k < 32; ++k) {
            float4 a  = *(const float4*)&At[k * 68 + ty * 4];
            float4 b0 = *(const float4*)&Bs[k * 128 + tx * 8];
            float4 b1v = *(const float4*)&Bs[k * 128 + tx * 8 + 4];
            float av[4] = {a.x, a.y, a.z, a.w};
            float bv[8] = {b0.x, b0.y, b0.z, b0.w, b1v.x, b1v.y, b1v.z, b1v.w};
#pragma unroll
            for (int i = 0; i < 4; ++i)
#pragma unroll
                for (int j = 0; j < 8; ++j) acc[i][j] += av[i] * bv[j];
        }
        __syncthreads();
    }

    const int c0 = tx * 8;
    float4 bb0 = *(const float4*)&b1[c0];
    float4 bb1 = *(const float4*)&b1[c0 + 4];
    float bias[8] = {bb0.x, bb0.y, bb0.z, bb0.w, bb1.x, bb1.y, bb1.z, bb1.w};
#pragma unroll
    for (int i = 0; i < 4; ++i) {
        int rg = rowBase + ty * 4 + i;
        if (rg < N_NODES) {
            float o[8];
#pragma unroll
            for (int j = 0; j < 8; ++j) o[j] = fmaxf(acc[i][j] + bias[j], 0.f);
            *(float4*)&h[rg * 128 + c0 + 0] = make_float4(o[0], o[1], o[2], o[3]);
            *(float4*)&h[rg * 128 + c0 + 4] = make_float4(o[4], o[5], o[6], o[7]);
        }
    }
}

// Layer 2 matmuls: p = h @ W2l  (to be aggregated), q = h @ W2r + b2
__global__ __launch_bounds__(256) void l2_kernel(
        const float* __restrict__ h,
        const float* __restrict__ W2l, const float* __restrict__ W2r,
        const float* __restrict__ b2,
        float* __restrict__ p, float* __restrict__ q) {
    __shared__ float At[32 * 68];
    __shared__ float Bs[32 * 128];

    const int t = threadIdx.x;
    const int ty = t >> 4;
    const int tx = t & 15;
    const int rowBase = blockIdx.x * 64;

    float acc[4][8];
#pragma unroll
    for (int i = 0; i < 4; ++i)
#pragma unroll
        for (int j = 0; j < 8; ++j) acc[i][j] = 0.f;

    const int arow = t >> 2;
    const int akq  = (t & 3) * 8;
    const int grow = rowBase + arow;
    const bool avalid = grow < N_NODES;

    const int bk = t >> 3;
    const int bj = (t & 7) * 16;
    const float* BsrcBase = (bj < 64) ? W2l : W2r;
    const int bjj = bj & 63;

    for (int kt = 0; kt < 4; ++kt) {
        {
            float4 v0 = make_float4(0.f,0.f,0.f,0.f);
            float4 v1 = make_float4(0.f,0.f,0.f,0.f);
            if (avalid) {
                const float* Asrc = h + grow * 128 + kt * 32 + akq;
                v0 = *(const float4*)Asrc;
                v1 = *(const float4*)(Asrc + 4);
            }
            At[(akq + 0) * 68 + arow] = v0.x;
            At[(akq + 1) * 68 + arow] = v0.y;
            At[(akq + 2) * 68 + arow] = v0.z;
            At[(akq + 3) * 68 + arow] = v0.w;
            At[(akq + 4) * 68 + arow] = v1.x;
            At[(akq + 5) * 68 + arow] = v1.y;
            At[(akq + 6) * 68 + arow] = v1.z;
            At[(akq + 7) * 68 + arow] = v1.w;
        }
        {
            const int kg = kt * 32 + bk;
            const float* Bsrc = BsrcBase + kg * 64 + bjj;
            float4 u0 = *(const float4*)(Bsrc + 0);
            float4 u1 = *(const float4*)(Bsrc + 4);
            float4 u2 = *(const float4*)(Bsrc + 8);
            float4 u3 = *(const float4*)(Bsrc + 12);
            *(float4*)&Bs[bk * 128 + bj + 0]  = u0;
            *(float4*)&Bs[bk * 128 + bj + 4]  = u1;
            *(float4*)&Bs[bk * 128 + bj + 8]  = u2;
            *(float4*)&Bs[bk * 128 + bj + 12] = u3;
        }
        __syncthreads();
#pragma unroll
        for (int k = 0; k < 32; ++k) {
            float4 a  = *(const float4*)&At[k * 68 + ty * 4];
            float4 b0 = *(const float4*)&Bs[k * 128 + tx * 8];
            float4 b1v = *(const float4*)&Bs[k * 128 + tx * 8 + 4];
            float av[4] = {a.x, a.y, a.z, a.w};
            float bv[8] = {b0.x, b0.y, b0.z, b0.w, b1v.x, b1v.y, b1v.z, b1v.w};
#pragma unroll
            for (int i = 0; i < 4; ++i)
#pragma unroll
                for (int j = 0; j < 8; ++j) acc[i][j] += av[i] * bv[j];
        }
        __syncthreads();
    }

    const int c0 = tx * 8;
    if (tx < 8) {
#pragma unroll
        for (int i = 0; i < 4; ++i) {
            int rg = rowBase + ty * 4 + i;
            if (rg < N_NODES) {
                *(float4*)&p[rg * 64 + c0 + 0] =
                    make_float4(acc[i][0], acc[i][1], acc[i][2], acc[i][3]);
                *(float4*)&p[rg * 64 + c0 + 4] =
                    make_float4(acc[i][4], acc[i][5], acc[i][6], acc[i][7]);
            }
        }
    } else {
        const int cq = c0 - 64;
        float4 bb0 = *(const float4*)&b2[cq];
        float4 bb1 = *(const float4*)&b2[cq + 4];
        float bias[8] = {bb0.x, bb0.y, bb0.z, bb0.w, bb1.x, bb1.y, bb1.z, bb1.w};
#pragma unroll
        for (int i = 0; i < 4; ++i) {
            int rg = rowBase + ty * 4 + i;
            if (rg < N_NODES) {
                *(float4*)&q[rg * 64 + cq + 0] =
                    make_float4(acc[i][0] + bias[0], acc[i][1] + bias[1],
                                acc[i][2] + bias[2], acc[i][3] + bias[3]);
                *(float4*)&q[rg * 64 + cq + 4] =
                    make_float4(acc[i][4] + bias[4], acc[i][5] + bias[5],
                                acc[i][6] + bias[6], acc[i][7] + bias[7]);
            }
        }
    }
}

// out = agg2/cnt + q
__global__ __launch_bounds__(256) void final_kernel(
        const float* __restrict__ agg2, const int* __restrict__ counts,
        const float* __restrict__ q, float* __restrict__ out) {
    int i = blockIdx.x * blockDim.x + threadIdx.x;
    if (i >= N_NODES * 16) return;
    int node = i >> 4;
    int c = (i & 15) * 4;
    float inv = 1.0f / fmaxf((float)counts[node], 1.0f);
    float4 a = *(const float4*)&agg2[node * 64 + c];
    float4 qq = *(const float4*)&q[node * 64 + c];
    *(float4*)&out[node * 64 + c] =
        make_float4(a.x * inv + qq.x, a.y * inv + qq.y,
                    a.z * inv + qq.z, a.w * inv + qq.w);
}

extern "C" void kernel_launch(void* const* d_in, const int* in_sizes, int n_in,
                              void* d_out, int out_size, void* d_ws, size_t ws_size,
                              hipStream_t stream) {
    const float* x   = (const float*)d_in[0];
    const float* W1l = (const float*)d_in[1];
    const float* W1r = (const float*)d_in[2];
    const float* b1  = (const float*)d_in[3];
    const float* W2l = (const float*)d_in[4];
    const float* W2r = (const float*)d_in[5];
    const float* b2  = (const float*)d_in[6];
    const int*   ei  = (const int*)d_in[7];

    int*   wsi    = (int*)d_ws;
    float* wsf    = (float*)d_ws;
    int*   counts = wsi;                       // 100k ints
    int*   slots  = wsi + 102400;              // 6.4M ints
    int*   ovfc   = wsi + 6502400;             // 1 int
    int*   ovf    = wsi + 6502464;             // 8192 ints
    float* agg1   = wsf + 6512640;             // 6.4M (reused as p)
    float* p      = agg1;
    float* h      = wsf + 12912640;            // 12.8M
    float* agg2   = h;                         // reuses h after l2
    float* q      = wsf + 25712640;            // 6.4M
    float* out    = (float*)d_out;

    init_kernel<<<(N_NODES + 255) / 256, 256, 0, stream>>>(counts, ovfc);
    hist_bucket_kernel<<<(N_EDGES + 255) / 256, 256, 0, stream>>>(
        ei, counts, slots, ovfc, ovf);

    // layer-1 aggregation (raw sums)
    gather_kernel<<<(N_NODES + 3) / 4, 256, 0, stream>>>(x, counts, slots, agg1);
    ovf_scatter_kernel<<<64, 64, 0, stream>>>(x, ovf, ovfc, agg1);

    // h = relu(mean @ W1l + x @ W1r + b1)
    l1_kernel<<<(N_NODES + 63) / 64, 256, 0, stream>>>(x, agg1, counts, W1l, W1r, b1, h);
    // p = h @ W2l ; q = h @ W2r + b2   (p overwrites agg1, h still live)
    l2_kernel<<<(N_NODES + 63) / 64, 256, 0, stream>>>(h, W2l, W2r, b2, p, q);

    // layer-2 aggregation of p (agg2 reuses h's storage; h is dead now)
    gather_kernel<<<(N_NODES + 3) / 4, 256, 0, stream>>>(p, counts, slots, agg2);
    ovf_scatter_kernel<<<64, 64, 0, stream>>>(p, ovf, ovfc, agg2);

    // out = agg2/cnt + q
    final_kernel<<<(N_NODES * 16 + 255) / 256, 256, 0, stream>>>(agg2, counts, q, out);
}

// Round 3
// 334.816 us; speedup vs baseline: 2.0694x; 1.0677x over previous
//
#include <hip/hip_runtime.h>

#define N_NODES 100000
#define N_EDGES 1000000
#define DEG_CAP 64
#define OVF_CAP 4096
#define RSTRIDE 100352   // N_NODES rounded up to 512

// ws layout (4B units):
//   counts_r : int [0,        802816)    8 replicas x RSTRIDE
//   bases_r  : int [802816,  1605632)
//   counts   : int [1605632, 1705984)
//   pos8     : u8  [1705984, 1956352)    1M bytes
//   ovfc     : int [1956352]
//   ovf      : int [1956416, 1964608)
//   slots    : int [1964608, 8364608)    N*64
//   agg1/p   : f32 [8364608, 14764608)
//   h        : f32 [14764608, 27564608)
//   q        : f32 [27564608, 33964608)
// total 33,964,608 elems = 135.9 MB

__global__ __launch_bounds__(256) void init_kernel(int4* __restrict__ counts_r,
                                                   int* __restrict__ ovfc) {
    int i = blockIdx.x * blockDim.x + threadIdx.x;
    if (i < (8 * RSTRIDE) / 4) counts_r[i] = make_int4(0, 0, 0, 0);
    if (i == 0) *ovfc = 0;
}

// Phase 1: replicated histogram. Replica chosen by block (~XCD via %8 dispatch).
// Per-edge position within its replica stashed coalesced as u8.
__global__ __launch_bounds__(256) void hist_kernel(
        const int* __restrict__ ei, int* __restrict__ counts_r,
        unsigned char* __restrict__ pos8) {
    int e = blockIdx.x * blockDim.x + threadIdx.x;
    if (e >= N_EDGES) return;
    int d = ei[N_EDGES + e];
    int r = (e >> 8) & 7;
    int p = atomicAdd(&counts_r[r * RSTRIDE + d], 1);
    pos8[e] = (unsigned char)(p < 255 ? p : 255);
}

// Phase 2: per-node prefix over the 8 replicas -> bases + total degree.
__global__ __launch_bounds__(256) void scan_kernel(
        const int* __restrict__ counts_r, int* __restrict__ bases_r,
        int* __restrict__ counts) {
    int d = blockIdx.x * blockDim.x + threadIdx.x;
    if (d >= N_NODES) return;
    int base = 0;
#pragma unroll
    for (int r = 0; r < 8; ++r) {
        bases_r[r * RSTRIDE + d] = base;
        base += counts_r[r * RSTRIDE + d];
    }
    counts[d] = base;
}

// Phase 3: atomic-free slot fill. Sentinel (p8==255) or pos>=64 -> overflow.
// Note: written positions per replica are contiguous from its base, and any
// hole starts at base+255 >= 255 > DEG_CAP, so slots[0..min(deg,64)) is
// always fully valid without zeroing.
__global__ __launch_bounds__(256) void fill_kernel(
        const int* __restrict__ ei, const unsigned char* __restrict__ pos8,
        const int* __restrict__ bases_r, int* __restrict__ slots,
        int* __restrict__ ovfc, int* __restrict__ ovf) {
    int e = blockIdx.x * blockDim.x + threadIdx.x;
    if (e >= N_EDGES) return;
    int s = ei[e];
    int d = ei[N_EDGES + e];
    int r = (e >> 8) & 7;
    int p8 = pos8[e];
    int pos = bases_r[r * RSTRIDE + d] + p8;
    if (p8 < 255 && pos < DEG_CAP) {
        slots[d * DEG_CAP + pos] = s;
    } else {
        int o = atomicAdd(ovfc, 1);
        if (o < OVF_CAP) { ovf[o * 2] = s; ovf[o * 2 + 1] = d; }
    }
}

// One wave per node, lane = feature. Writes RAW SUM.
__global__ __launch_bounds__(256) void gather_kernel(
        const float* __restrict__ feat, const int* __restrict__ counts,
        const int* __restrict__ slots, float* __restrict__ agg) {
    int wid = blockIdx.x * 4 + (threadIdx.x >> 6);
    int f = threadIdx.x & 63;
    if (wid >= N_NODES) return;
    int deg = counts[wid];
    int dcap = min(deg, DEG_CAP);
    int ids = slots[wid * DEG_CAP + f];
    float sum = 0.f;
    int j = 0;
    for (; j + 4 <= dcap; j += 4) {
        int s0 = __shfl(ids, j + 0);
        int s1 = __shfl(ids, j + 1);
        int s2 = __shfl(ids, j + 2);
        int s3 = __shfl(ids, j + 3);
        float v0 = feat[s0 * 64 + f];
        float v1 = feat[s1 * 64 + f];
        float v2 = feat[s2 * 64 + f];
        float v3 = feat[s3 * 64 + f];
        sum += v0 + v1 + v2 + v3;
    }
    for (; j < dcap; ++j) {
        int s = __shfl(ids, j);
        sum += feat[s * 64 + f];
    }
    agg[wid * 64 + f] = sum;
}

// Layer-1 overflow: add raw feat into agg1 (runs after gather_kernel).
__global__ __launch_bounds__(64) void ovf_scatter_kernel(
        const float* __restrict__ feat, const int* __restrict__ ovf,
        const int* __restrict__ ovfc, float* __restrict__ agg) {
    int n = *ovfc;
    if (n > OVF_CAP) n = OVF_CAP;
    for (int idx = blockIdx.x; idx < n; idx += gridDim.x) {
        int s = ovf[idx * 2];
        int d = ovf[idx * 2 + 1];
        atomicAdd(&agg[d * 64 + threadIdx.x], feat[s * 64 + threadIdx.x]);
    }
}

// Fused layer-2 aggregation + epilogue: out = sum(p[nbrs])/cnt + q
__global__ __launch_bounds__(256) void gather_final_kernel(
        const float* __restrict__ p, const int* __restrict__ counts,
        const int* __restrict__ slots, const float* __restrict__ q,
        float* __restrict__ out) {
    int wid = blockIdx.x * 4 + (threadIdx.x >> 6);
    int f = threadIdx.x & 63;
    if (wid >= N_NODES) return;
    int deg = counts[wid];
    int dcap = min(deg, DEG_CAP);
    int ids = slots[wid * DEG_CAP + f];
    float sum = 0.f;
    int j = 0;
    for (; j + 4 <= dcap; j += 4) {
        int s0 = __shfl(ids, j + 0);
        int s1 = __shfl(ids, j + 1);
        int s2 = __shfl(ids, j + 2);
        int s3 = __shfl(ids, j + 3);
        float v0 = p[s0 * 64 + f];
        float v1 = p[s1 * 64 + f];
        float v2 = p[s2 * 64 + f];
        float v3 = p[s3 * 64 + f];
        sum += v0 + v1 + v2 + v3;
    }
    for (; j < dcap; ++j) {
        int s = __shfl(ids, j);
        sum += p[s * 64 + f];
    }
    float inv = 1.0f / fmaxf((float)deg, 1.0f);
    out[wid * 64 + f] = sum * inv + q[wid * 64 + f];
}

// Layer-2 overflow fix-up (additive, runs after gather_final).
__global__ __launch_bounds__(64) void ovf_fixup_kernel(
        const float* __restrict__ p, const int* __restrict__ ovf,
        const int* __restrict__ ovfc, const int* __restrict__ counts,
        float* __restrict__ out) {
    int n = *ovfc;
    if (n > OVF_CAP) n = OVF_CAP;
    for (int idx = blockIdx.x; idx < n; idx += gridDim.x) {
        int s = ovf[idx * 2];
        int d = ovf[idx * 2 + 1];
        float inv = 1.0f / fmaxf((float)counts[d], 1.0f);
        atomicAdd(&out[d * 64 + threadIdx.x],
                  p[s * 64 + threadIdx.x] * inv);
    }
}

// Layer 1: h = relu( (agg1/cnt) @ W1l + x @ W1r + b1 )
__global__ __launch_bounds__(256) void l1_kernel(
        const float* __restrict__ x, const float* __restrict__ agg1,
        const int* __restrict__ counts,
        const float* __restrict__ W1l, const float* __restrict__ W1r,
        const float* __restrict__ b1, float* __restrict__ h) {
    __shared__ float At[32 * 68];
    __shared__ float Bs[32 * 128];

    const int t = threadIdx.x;
    const int ty = t >> 4;
    const int tx = t & 15;
    const int rowBase = blockIdx.x * 64;

    float acc[4][8];
#pragma unroll
    for (int i = 0; i < 4; ++i)
#pragma unroll
        for (int j = 0; j < 8; ++j) acc[i][j] = 0.f;

    const int arow = t >> 2;
    const int akq  = (t & 3) * 8;
    const int grow = rowBase + arow;
    const bool avalid = grow < N_NODES;
    float inv = 0.f;
    if (avalid) inv = 1.0f / fmaxf((float)counts[grow], 1.0f);

    const int bk = t >> 3;
    const int bj = (t & 7) * 16;

    for (int kt = 0; kt < 4; ++kt) {
        {
            float4 v0 = make_float4(0.f,0.f,0.f,0.f);
            float4 v1 = make_float4(0.f,0.f,0.f,0.f);
            if (avalid) {
                const float* Asrc = (kt < 2)
                    ? (agg1 + grow * 64 + kt * 32 + akq)
                    : (x    + grow * 64 + (kt - 2) * 32 + akq);
                v0 = *(const float4*)Asrc;
                v1 = *(const float4*)(Asrc + 4);
                if (kt < 2) {
                    v0.x *= inv; v0.y *= inv; v0.z *= inv; v0.w *= inv;
                    v1.x *= inv; v1.y *= inv; v1.z *= inv; v1.w *= inv;
                }
            }
            At[(akq + 0) * 68 + arow] = v0.x;
            At[(akq + 1) * 68 + arow] = v0.y;
            At[(akq + 2) * 68 + arow] = v0.z;
            At[(akq + 3) * 68 + arow] = v0.w;
            At[(akq + 4) * 68 + arow] = v1.x;
            At[(akq + 5) * 68 + arow] = v1.y;
            At[(akq + 6) * 68 + arow] = v1.z;
            At[(akq + 7) * 68 + arow] = v1.w;
        }
        {
            const int kg = kt * 32 + bk;
            const float* Bsrc = (kg < 64)
                ? (W1l + kg * 128 + bj)
                : (W1r + (kg - 64) * 128 + bj);
            float4 u0 = *(const float4*)(Bsrc + 0);
            float4 u1 = *(const float4*)(Bsrc + 4);
            float4 u2 = *(const float4*)(Bsrc + 8);
            float4 u3 = *(const float4*)(Bsrc + 12);
            *(float4*)&Bs[bk * 128 + bj + 0]  = u0;
            *(float4*)&Bs[bk * 128 + bj + 4]  = u1;
            *(float4*)&Bs[bk * 128 + bj + 8]  = u2;
            *(float4*)&Bs[bk * 128 + bj + 12] = u3;
        }
        __syncthreads();
#pragma unroll
        for (int k = 0; k < 32; ++k) {
            float4 a  = *(const float4*)&At[k * 68 + ty * 4];
            float4 b0 = *(const float4*)&Bs[k * 128 + tx * 8];
            float4 b1v = *(const float4*)&Bs[k * 128 + tx * 8 + 4];
            float av[4] = {a.x, a.y, a.z, a.w};
            float bv[8] = {b0.x, b0.y, b0.z, b0.w, b1v.x, b1v.y, b1v.z, b1v.w};
#pragma unroll
            for (int i = 0; i < 4; ++i)
#pragma unroll
                for (int j = 0; j < 8; ++j) acc[i][j] += av[i] * bv[j];
        }
        __syncthreads();
    }

    const int c0 = tx * 8;
    float4 bb0 = *(const float4*)&b1[c0];
    float4 bb1 = *(const float4*)&b1[c0 + 4];
    float bias[8] = {bb0.x, bb0.y, bb0.z, bb0.w, bb1.x, bb1.y, bb1.z, bb1.w};
#pragma unroll
    for (int i = 0; i < 4; ++i) {
        int rg = rowBase + ty * 4 + i;
        if (rg < N_NODES) {
            float o[8];
#pragma unroll
            for (int j = 0; j < 8; ++j) o[j] = fmaxf(acc[i][j] + bias[j], 0.f);
            *(float4*)&h[rg * 128 + c0 + 0] = make_float4(o[0], o[1], o[2], o[3]);
            *(float4*)&h[rg * 128 + c0 + 4] = make_float4(o[4], o[5], o[6], o[7]);
        }
    }
}

// Layer 2 matmuls: p = h @ W2l ; q = h @ W2r + b2
__global__ __launch_bounds__(256) void l2_kernel(
        const float* __restrict__ h,
        const float* __restrict__ W2l, const float* __restrict__ W2r,
        const float* __restrict__ b2,
        float* __restrict__ p, float* __restrict__ q) {
    __shared__ float At[32 * 68];
    __shared__ float Bs[32 * 128];

    const int t = threadIdx.x;
    const int ty = t >> 4;
    const int tx = t & 15;
    const int rowBase = blockIdx.x * 64;

    float acc[4][8];
#pragma unroll
    for (int i = 0; i < 4; ++i)
#pragma unroll
        for (int j = 0; j < 8; ++j) acc[i][j] = 0.f;

    const int arow = t >> 2;
    const int akq  = (t & 3) * 8;
    const int grow = rowBase + arow;
    const bool avalid = grow < N_NODES;

    const int bk = t >> 3;
    const int bj = (t & 7) * 16;
    const float* BsrcBase = (bj < 64) ? W2l : W2r;
    const int bjj = bj & 63;

    for (int kt = 0; kt < 4; ++kt) {
        {
            float4 v0 = make_float4(0.f,0.f,0.f,0.f);
            float4 v1 = make_float4(0.f,0.f,0.f,0.f);
            if (avalid) {
                const float* Asrc = h + grow * 128 + kt * 32 + akq;
                v0 = *(const float4*)Asrc;
                v1 = *(const float4*)(Asrc + 4);
            }
            At[(akq + 0) * 68 + arow] = v0.x;
            At[(akq + 1) * 68 + arow] = v0.y;
            At[(akq + 2) * 68 + arow] = v0.z;
            At[(akq + 3) * 68 + arow] = v0.w;
            At[(akq + 4) * 68 + arow] = v1.x;
            At[(akq + 5) * 68 + arow] = v1.y;
            At[(akq + 6) * 68 + arow] = v1.z;
            At[(akq + 7) * 68 + arow] = v1.w;
        }
        {
            const int kg = kt * 32 + bk;
            const float* Bsrc = BsrcBase + kg * 64 + bjj;
            float4 u0 = *(const float4*)(Bsrc + 0);
            float4 u1 = *(const float4*)(Bsrc + 4);
            float4 u2 = *(const float4*)(Bsrc + 8);
            float4 u3 = *(const float4*)(Bsrc + 12);
            *(float4*)&Bs[bk * 128 + bj + 0]  = u0;
            *(float4*)&Bs[bk * 128 + bj + 4]  = u1;
            *(float4*)&Bs[bk * 128 + bj + 8]  = u2;
            *(float4*)&Bs[bk * 128 + bj + 12] = u3;
        }
        __syncthreads();
#pragma unroll
        for (int k = 0; k < 32; ++k) {
            float4 a  = *(const float4*)&At[k * 68 + ty * 4];
            float4 b0 = *(const float4*)&Bs[k * 128 + tx * 8];
            float4 b1v = *(const float4*)&Bs[k * 128 + tx * 8 + 4];
            float av[4] = {a.x, a.y, a.z, a.w};
            float bv[8] = {b0.x, b0.y, b0.z, b0.w, b1v.x, b1v.y, b1v.z, b1v.w};
#pragma unroll
            for (int i = 0; i < 4; ++i)
#pragma unroll
                for (int j = 0; j < 8; ++j) acc[i][j] += av[i] * bv[j];
        }
        __syncthreads();
    }

    const int c0 = tx * 8;
    if (tx < 8) {
#pragma unroll
        for (int i = 0; i < 4; ++i) {
            int rg = rowBase + ty * 4 + i;
            if (rg < N_NODES) {
                *(float4*)&p[rg * 64 + c0 + 0] =
                    make_float4(acc[i][0], acc[i][1], acc[i][2], acc[i][3]);
                *(float4*)&p[rg * 64 + c0 + 4] =
                    make_float4(acc[i][4], acc[i][5], acc[i][6], acc[i][7]);
            }
        }
    } else {
        const int cq = c0 - 64;
        float4 bb0 = *(const float4*)&b2[cq];
        float4 bb1 = *(const float4*)&b2[cq + 4];
        float bias[8] = {bb0.x, bb0.y, bb0.z, bb0.w, bb1.x, bb1.y, bb1.z, bb1.w};
#pragma unroll
        for (int i = 0; i < 4; ++i) {
            int rg = rowBase + ty * 4 + i;
            if (rg < N_NODES) {
                *(float4*)&q[rg * 64 + cq + 0] =
                    make_float4(acc[i][0] + bias[0], acc[i][1] + bias[1],
                                acc[i][2] + bias[2], acc[i][3] + bias[3]);
                *(float4*)&q[rg * 64 + cq + 4] =
                    make_float4(acc[i][4] + bias[4], acc[i][5] + bias[5],
                                acc[i][6] + bias[6], acc[i][7] + bias[7]);
            }
        }
    }
}

extern "C" void kernel_launch(void* const* d_in, const int* in_sizes, int n_in,
                              void* d_out, int out_size, void* d_ws, size_t ws_size,
                              hipStream_t stream) {
    const float* x   = (const float*)d_in[0];
    const float* W1l = (const float*)d_in[1];
    const float* W1r = (const float*)d_in[2];
    const float* b1  = (const float*)d_in[3];
    const float* W2l = (const float*)d_in[4];
    const float* W2r = (const float*)d_in[5];
    const float* b2  = (const float*)d_in[6];
    const int*   ei  = (const int*)d_in[7];

    int*   wsi      = (int*)d_ws;
    float* wsf      = (float*)d_ws;
    int*   counts_r = wsi;                         // 8*RSTRIDE
    int*   bases_r  = wsi + 802816;
    int*   counts   = wsi + 1605632;
    unsigned char* pos8 = (unsigned char*)(wsi + 1705984);
    int*   ovfc     = wsi + 1956352;
    int*   ovf      = wsi + 1956416;
    int*   slots    = wsi + 1964608;               // 6.4M
    float* agg1     = wsf + 8364608;               // 6.4M (reused as p)
    float* p        = agg1;
    float* h        = wsf + 14764608;              // 12.8M
    float* q        = wsf + 27564608;              // 6.4M
    float* out      = (float*)d_out;

    init_kernel<<<(8 * RSTRIDE / 4 + 255) / 256, 256, 0, stream>>>(
        (int4*)counts_r, ovfc);
    hist_kernel<<<(N_EDGES + 255) / 256, 256, 0, stream>>>(ei, counts_r, pos8);
    scan_kernel<<<(N_NODES + 255) / 256, 256, 0, stream>>>(counts_r, bases_r, counts);
    fill_kernel<<<(N_EDGES + 255) / 256, 256, 0, stream>>>(
        ei, pos8, bases_r, slots, ovfc, ovf);

    // layer-1 aggregation (raw sums) + overflow
    gather_kernel<<<(N_NODES + 3) / 4, 256, 0, stream>>>(x, counts, slots, agg1);
    ovf_scatter_kernel<<<64, 64, 0, stream>>>(x, ovf, ovfc, agg1);

    // h = relu(mean @ W1l + x @ W1r + b1)
    l1_kernel<<<(N_NODES + 63) / 64, 256, 0, stream>>>(x, agg1, counts, W1l, W1r, b1, h);
    // p = h @ W2l ; q = h @ W2r + b2   (p overwrites agg1)
    l2_kernel<<<(N_NODES + 63) / 64, 256, 0, stream>>>(h, W2l, W2r, b2, p, q);

    // fused layer-2 aggregation + epilogue, then overflow fix-up
    gather_final_kernel<<<(N_NODES + 3) / 4, 256, 0, stream>>>(
        p, counts, slots, q, out);
    ovf_fixup_kernel<<<64, 64, 0, stream>>>(p, ovf, ovfc, counts, out);
}

// Round 4
// 322.500 us; speedup vs baseline: 2.1485x; 1.0382x over previous
//
#include <hip/hip_runtime.h>

#define N_NODES 100000
#define N_EDGES 1000000
#define DEG_CAP 64
#define OVF_CAP 4096
#define RSTRIDE 100352   // N_NODES rounded up to 512

typedef __attribute__((ext_vector_type(8))) short bf16x8;
typedef __attribute__((ext_vector_type(4))) float f32x4;

// ws layout (4B units):
//   counts_r : int [0,        802816)    8 replicas x RSTRIDE
//   bases_r  : int [802816,  1605632)
//   counts   : int [1605632, 1705984)
//   pos8     : u8  [1705984, 1956352)
//   ovfc     : int [1956352]
//   ovf      : int [1956416, 1964608)
//   Bf1      : s16 [1964608, 1980992)    32768 halfs (frag-ordered hi/lo)
//   Bf2      : s16 [1980992, 1997376)
//   slots    : int [1997376, 8397376)    N*64
//   mean1/p  : f32 [8397376, 14797376)
//   h        : f32 [14797376, 27597376)
//   q        : f32 [27597376, 33997376)
// total 33,997,376 elems = 136 MB

__global__ __launch_bounds__(256) void init_kernel(int4* __restrict__ counts_r,
                                                   int* __restrict__ ovfc) {
    int i = blockIdx.x * blockDim.x + threadIdx.x;
    if (i < (8 * RSTRIDE) / 4) counts_r[i] = make_int4(0, 0, 0, 0);
    if (i == 0) *ovfc = 0;
}

// Pre-split weights into MFMA-fragment-ordered bf16 hi/lo.
// Bf layout: [(c*4+kc)*2 + term][lane][j]  (512 halfs per chunk)
//   element (k,n): c=n>>4, kc=k>>5, lane=((k>>3)&3)<<4 | (n&15), j=k&7
__global__ __launch_bounds__(256) void prep_b_kernel(
        const float* __restrict__ W1l, const float* __restrict__ W1r,
        const float* __restrict__ W2l, const float* __restrict__ W2r,
        short* __restrict__ Bf1, short* __restrict__ Bf2) {
    int idx = blockIdx.x * blockDim.x + threadIdx.x;
    if (idx >= 32768) return;
    int g = idx >> 14;
    int e = idx & 16383;
    int k = e >> 7;
    int n = e & 127;
    float v;
    if (g == 0) v = (k < 64) ? W1l[k * 128 + n] : W1r[(k - 64) * 128 + n];
    else        v = (n < 64) ? W2l[k * 64 + n]  : W2r[k * 64 + (n - 64)];
    unsigned u = __float_as_uint(v);
    unsigned hb = u >> 16;
    float vh = __uint_as_float(hb << 16);
    unsigned lb = __float_as_uint(v - vh) >> 16;
    int c = n >> 4, kc = k >> 5;
    int lane = (((k >> 3) & 3) << 4) | (n & 15);
    int j = k & 7;
    short* base = g ? Bf2 : Bf1;
    base[((c * 4 + kc) * 2 + 0) * 512 + lane * 8 + j] = (short)hb;
    base[((c * 4 + kc) * 2 + 1) * 512 + lane * 8 + j] = (short)lb;
}

// Phase 1: replicated histogram (8 replicas, replica by edge-block ~ XCD).
__global__ __launch_bounds__(256) void hist_kernel(
        const int* __restrict__ ei, int* __restrict__ counts_r,
        unsigned char* __restrict__ pos8) {
    int e = blockIdx.x * blockDim.x + threadIdx.x;
    if (e >= N_EDGES) return;
    int d = ei[N_EDGES + e];
    int r = (e >> 8) & 7;
    int p = atomicAdd(&counts_r[r * RSTRIDE + d], 1);
    pos8[e] = (unsigned char)(p < 255 ? p : 255);
}

// Phase 2: per-node prefix over the 8 replicas.
__global__ __launch_bounds__(256) void scan_kernel(
        const int* __restrict__ counts_r, int* __restrict__ bases_r,
        int* __restrict__ counts) {
    int d = blockIdx.x * blockDim.x + threadIdx.x;
    if (d >= N_NODES) return;
    int base = 0;
#pragma unroll
    for (int r = 0; r < 8; ++r) {
        bases_r[r * RSTRIDE + d] = base;
        base += counts_r[r * RSTRIDE + d];
    }
    counts[d] = base;
}

// Phase 3: atomic-free slot fill; overflow funnel for deg>64.
__global__ __launch_bounds__(256) void fill_kernel(
        const int* __restrict__ ei, const unsigned char* __restrict__ pos8,
        const int* __restrict__ bases_r, int* __restrict__ slots,
        int* __restrict__ ovfc, int* __restrict__ ovf) {
    int e = blockIdx.x * blockDim.x + threadIdx.x;
    if (e >= N_EDGES) return;
    int s = ei[e];
    int d = ei[N_EDGES + e];
    int r = (e >> 8) & 7;
    int p8 = pos8[e];
    int pos = bases_r[r * RSTRIDE + d] + p8;
    if (p8 < 255 && pos < DEG_CAP) {
        slots[d * DEG_CAP + pos] = s;
    } else {
        int o = atomicAdd(ovfc, 1);
        if (o < OVF_CAP) { ovf[o * 2] = s; ovf[o * 2 + 1] = d; }
    }
}

// One wave per node, lane = feature. Writes the MEAN directly.
__global__ __launch_bounds__(256) void gather_kernel(
        const float* __restrict__ feat, const int* __restrict__ counts,
        const int* __restrict__ slots, float* __restrict__ agg) {
    int wid = blockIdx.x * 4 + (threadIdx.x >> 6);
    int f = threadIdx.x & 63;
    if (wid >= N_NODES) return;
    int deg = counts[wid];
    int dcap = min(deg, DEG_CAP);
    int ids = slots[wid * DEG_CAP + f];
    float sum = 0.f;
    int j = 0;
    for (; j + 4 <= dcap; j += 4) {
        int s0 = __shfl(ids, j + 0);
        int s1 = __shfl(ids, j + 1);
        int s2 = __shfl(ids, j + 2);
        int s3 = __shfl(ids, j + 3);
        float v0 = feat[s0 * 64 + f];
        float v1 = feat[s1 * 64 + f];
        float v2 = feat[s2 * 64 + f];
        float v3 = feat[s3 * 64 + f];
        sum += v0 + v1 + v2 + v3;
    }
    for (; j < dcap; ++j) {
        int s = __shfl(ids, j);
        sum += feat[s * 64 + f];
    }
    float inv = 1.0f / fmaxf((float)deg, 1.0f);
    agg[wid * 64 + f] = sum * inv;
}

// Layer-1 overflow: add feat*inv into mean (runs after gather_kernel).
__global__ __launch_bounds__(64) void ovf_scatter_kernel(
        const float* __restrict__ feat, const int* __restrict__ ovf,
        const int* __restrict__ ovfc, const int* __restrict__ counts,
        float* __restrict__ agg) {
    int n = *ovfc;
    if (n > OVF_CAP) n = OVF_CAP;
    for (int idx = blockIdx.x; idx < n; idx += gridDim.x) {
        int s = ovf[idx * 2];
        int d = ovf[idx * 2 + 1];
        float inv = 1.0f / fmaxf((float)counts[d], 1.0f);
        atomicAdd(&agg[d * 64 + threadIdx.x], feat[s * 64 + threadIdx.x] * inv);
    }
}

// Layer 1 MFMA: h = relu( [mean|x] @ [W1l;W1r] + b1 )
// Split-bf16 (3-term) 16x16x32 MFMA; no LDS, no barriers.
// Wave w owns rows blk*64 + w*16 .. +15, all 128 cols (8 col-tiles).
__global__ __launch_bounds__(256) void l1_mfma_kernel(
        const float* __restrict__ mean1, const float* __restrict__ x,
        const short* __restrict__ Bf1, const float* __restrict__ b1,
        float* __restrict__ h) {
    const int w = threadIdx.x >> 6;
    const int l = threadIdx.x & 63;
    const int lane15 = l & 15;
    const int quad = l >> 4;
    const int row = blockIdx.x * 64 + w * 16 + lane15;
    const bool rv = row < N_NODES;

    bf16x8 ah[4], al[4];
#pragma unroll
    for (int kc = 0; kc < 4; ++kc) {
        float4 v0 = make_float4(0.f, 0.f, 0.f, 0.f);
        float4 v1 = make_float4(0.f, 0.f, 0.f, 0.f);
        if (rv) {
            const float* src = (kc < 2)
                ? (mean1 + row * 64 + kc * 32 + quad * 8)
                : (x     + row * 64 + (kc - 2) * 32 + quad * 8);
            v0 = *(const float4*)src;
            v1 = *(const float4*)(src + 4);
        }
        float f[8] = {v0.x, v0.y, v0.z, v0.w, v1.x, v1.y, v1.z, v1.w};
#pragma unroll
        for (int j = 0; j < 8; ++j) {
            unsigned u = __float_as_uint(f[j]);
            unsigned hb = u >> 16;
            float fh = __uint_as_float(hb << 16);
            unsigned lb = __float_as_uint(f[j] - fh) >> 16;
            ah[kc][j] = (short)hb;
            al[kc][j] = (short)lb;
        }
    }

    f32x4 acc[8];
#pragma unroll
    for (int c = 0; c < 8; ++c) acc[c] = (f32x4){0.f, 0.f, 0.f, 0.f};

#pragma unroll
    for (int kc = 0; kc < 4; ++kc) {
#pragma unroll
        for (int c = 0; c < 8; ++c) {
            const short* bp = Bf1 + ((c * 4 + kc) * 2) * 512 + l * 8;
            bf16x8 bh = *(const bf16x8*)bp;
            bf16x8 bl = *(const bf16x8*)(bp + 512);
            acc[c] = __builtin_amdgcn_mfma_f32_16x16x32_bf16(ah[kc], bh, acc[c], 0, 0, 0);
            acc[c] = __builtin_amdgcn_mfma_f32_16x16x32_bf16(al[kc], bh, acc[c], 0, 0, 0);
            acc[c] = __builtin_amdgcn_mfma_f32_16x16x32_bf16(ah[kc], bl, acc[c], 0, 0, 0);
        }
    }

    // C layout: col = c*16 + lane15, row = quad*4 + i
    const int rbase = blockIdx.x * 64 + w * 16 + quad * 4;
#pragma unroll
    for (int c = 0; c < 8; ++c) {
        float bias = b1[c * 16 + lane15];
#pragma unroll
        for (int i = 0; i < 4; ++i) {
            int r = rbase + i;
            if (r < N_NODES)
                h[r * 128 + c * 16 + lane15] = fmaxf(acc[c][i] + bias, 0.f);
        }
    }
}

// Layer 2 MFMA: [p|q] = h @ [W2l|W2r] (+ b2 on q half)
__global__ __launch_bounds__(256) void l2_mfma_kernel(
        const float* __restrict__ h, const short* __restrict__ Bf2,
        const float* __restrict__ b2,
        float* __restrict__ p, float* __restrict__ q) {
    const int w = threadIdx.x >> 6;
    const int l = threadIdx.x & 63;
    const int lane15 = l & 15;
    const int quad = l >> 4;
    const int row = blockIdx.x * 64 + w * 16 + lane15;
    const bool rv = row < N_NODES;

    bf16x8 ah[4], al[4];
#pragma unroll
    for (int kc = 0; kc < 4; ++kc) {
        float4 v0 = make_float4(0.f, 0.f, 0.f, 0.f);
        float4 v1 = make_float4(0.f, 0.f, 0.f, 0.f);
        if (rv) {
            const float* src = h + row * 128 + kc * 32 + quad * 8;
            v0 = *(const float4*)src;
            v1 = *(const float4*)(src + 4);
        }
        float f[8] = {v0.x, v0.y, v0.z, v0.w, v1.x, v1.y, v1.z, v1.w};
#pragma unroll
        for (int j = 0; j < 8; ++j) {
            unsigned u = __float_as_uint(f[j]);
            unsigned hb = u >> 16;
            float fh = __uint_as_float(hb << 16);
            unsigned lb = __float_as_uint(f[j] - fh) >> 16;
            ah[kc][j] = (short)hb;
            al[kc][j] = (short)lb;
        }
    }

    f32x4 acc[8];
#pragma unroll
    for (int c = 0; c < 8; ++c) acc[c] = (f32x4){0.f, 0.f, 0.f, 0.f};

#pragma unroll
    for (int kc = 0; kc < 4; ++kc) {
#pragma unroll
        for (int c = 0; c < 8; ++c) {
            const short* bp = Bf2 + ((c * 4 + kc) * 2) * 512 + l * 8;
            bf16x8 bh = *(const bf16x8*)bp;
            bf16x8 bl = *(const bf16x8*)(bp + 512);
            acc[c] = __builtin_amdgcn_mfma_f32_16x16x32_bf16(ah[kc], bh, acc[c], 0, 0, 0);
            acc[c] = __builtin_amdgcn_mfma_f32_16x16x32_bf16(al[kc], bh, acc[c], 0, 0, 0);
            acc[c] = __builtin_amdgcn_mfma_f32_16x16x32_bf16(ah[kc], bl, acc[c], 0, 0, 0);
        }
    }

    const int rbase = blockIdx.x * 64 + w * 16 + quad * 4;
#pragma unroll
    for (int c = 0; c < 8; ++c) {
        if (c < 4) {
#pragma unroll
            for (int i = 0; i < 4; ++i) {
                int r = rbase + i;
                if (r < N_NODES)
                    p[r * 64 + c * 16 + lane15] = acc[c][i];
            }
        } else {
            float bias = b2[(c - 4) * 16 + lane15];
#pragma unroll
            for (int i = 0; i < 4; ++i) {
                int r = rbase + i;
                if (r < N_NODES)
                    q[r * 64 + (c - 4) * 16 + lane15] = acc[c][i] + bias;
            }
        }
    }
}

// Fused layer-2 aggregation + epilogue: out = sum(p[nbrs])/cnt + q
__global__ __launch_bounds__(256) void gather_final_kernel(
        const float* __restrict__ p, const int* __restrict__ counts,
        const int* __restrict__ slots, const float* __restrict__ q,
        float* __restrict__ out) {
    int wid = blockIdx.x * 4 + (threadIdx.x >> 6);
    int f = threadIdx.x & 63;
    if (wid >= N_NODES) return;
    int deg = counts[wid];
    int dcap = min(deg, DEG_CAP);
    int ids = slots[wid * DEG_CAP + f];
    float sum = 0.f;
    int j = 0;
    for (; j + 4 <= dcap; j += 4) {
        int s0 = __shfl(ids, j + 0);
        int s1 = __shfl(ids, j + 1);
        int s2 = __shfl(ids, j + 2);
        int s3 = __shfl(ids, j + 3);
        float v0 = p[s0 * 64 + f];
        float v1 = p[s1 * 64 + f];
        float v2 = p[s2 * 64 + f];
        float v3 = p[s3 * 64 + f];
        sum += v0 + v1 + v2 + v3;
    }
    for (; j < dcap; ++j) {
        int s = __shfl(ids, j);
        sum += p[s * 64 + f];
    }
    float inv = 1.0f / fmaxf((float)deg, 1.0f);
    out[wid * 64 + f] = sum * inv + q[wid * 64 + f];
}

// Layer-2 overflow fix-up (additive).
__global__ __launch_bounds__(64) void ovf_fixup_kernel(
        const float* __restrict__ p, const int* __restrict__ ovf,
        const int* __restrict__ ovfc, const int* __restrict__ counts,
        float* __restrict__ out) {
    int n = *ovfc;
    if (n > OVF_CAP) n = OVF_CAP;
    for (int idx = blockIdx.x; idx < n; idx += gridDim.x) {
        int s = ovf[idx * 2];
        int d = ovf[idx * 2 + 1];
        float inv = 1.0f / fmaxf((float)counts[d], 1.0f);
        atomicAdd(&out[d * 64 + threadIdx.x],
                  p[s * 64 + threadIdx.x] * inv);
    }
}

extern "C" void kernel_launch(void* const* d_in, const int* in_sizes, int n_in,
                              void* d_out, int out_size, void* d_ws, size_t ws_size,
                              hipStream_t stream) {
    const float* x   = (const float*)d_in[0];
    const float* W1l = (const float*)d_in[1];
    const float* W1r = (const float*)d_in[2];
    const float* b1  = (const float*)d_in[3];
    const float* W2l = (const float*)d_in[4];
    const float* W2r = (const float*)d_in[5];
    const float* b2  = (const float*)d_in[6];
    const int*   ei  = (const int*)d_in[7];

    int*   wsi      = (int*)d_ws;
    float* wsf      = (float*)d_ws;
    int*   counts_r = wsi;
    int*   bases_r  = wsi + 802816;
    int*   counts   = wsi + 1605632;
    unsigned char* pos8 = (unsigned char*)(wsi + 1705984);
    int*   ovfc     = wsi + 1956352;
    int*   ovf      = wsi + 1956416;
    short* Bf1      = (short*)(wsi + 1964608);
    short* Bf2      = (short*)(wsi + 1980992);
    int*   slots    = wsi + 1997376;
    float* mean1    = wsf + 8397376;     // reused as p after l1 consumes it
    float* p        = mean1;
    float* h        = wsf + 14797376;
    float* q        = wsf + 27597376;
    float* out      = (float*)d_out;

    init_kernel<<<(8 * RSTRIDE / 4 + 255) / 256, 256, 0, stream>>>(
        (int4*)counts_r, ovfc);
    prep_b_kernel<<<128, 256, 0, stream>>>(W1l, W1r, W2l, W2r, Bf1, Bf2);
    hist_kernel<<<(N_EDGES + 255) / 256, 256, 0, stream>>>(ei, counts_r, pos8);
    scan_kernel<<<(N_NODES + 255) / 256, 256, 0, stream>>>(counts_r, bases_r, counts);
    fill_kernel<<<(N_EDGES + 255) / 256, 256, 0, stream>>>(
        ei, pos8, bases_r, slots, ovfc, ovf);

    // layer-1 aggregation -> mean, + overflow
    gather_kernel<<<(N_NODES + 3) / 4, 256, 0, stream>>>(x, counts, slots, mean1);
    ovf_scatter_kernel<<<64, 64, 0, stream>>>(x, ovf, ovfc, counts, mean1);

    // h = relu([mean|x] @ [W1l;W1r] + b1)
    l1_mfma_kernel<<<(N_NODES + 63) / 64, 256, 0, stream>>>(
        mean1, x, Bf1, b1, h);
    // p = h @ W2l ; q = h @ W2r + b2   (p overwrites mean1)
    l2_mfma_kernel<<<(N_NODES + 63) / 64, 256, 0, stream>>>(h, Bf2, b2, p, q);

    // fused layer-2 aggregation + epilogue, then overflow fix-up
    gather_final_kernel<<<(N_NODES + 3) / 4, 256, 0, stream>>>(
        p, counts, slots, q, out);
    ovf_fixup_kernel<<<64, 64, 0, stream>>>(p, ovf, ovfc, counts, out);
}

// Round 6
// 306.443 us; speedup vs baseline: 2.2611x; 1.0524x over previous
//
#include <hip/hip_runtime.h>

#define N_NODES 100000
#define N_EDGES 1000000
#define DEG_CAP 64
#define OVF_CAP 4096
#define RSTRIDE 100352   // N_NODES rounded up to 512

typedef __attribute__((ext_vector_type(8))) short bf16x8;
typedef __attribute__((ext_vector_type(4))) float f32x4;

__device__ __forceinline__ unsigned short f2bf(float f) {
    unsigned u = __float_as_uint(f);
    return (unsigned short)((u + 0x7FFF + ((u >> 16) & 1)) >> 16);
}
__device__ __forceinline__ float bf2f(unsigned short b) {
    return __uint_as_float(((unsigned)b) << 16);
}

// ws layout (4B units):
//   counts_r : int [0,        802816)    8 replicas x RSTRIDE
//   bases_r  : int [802816,  1605632)
//   counts   : int [1605632, 1705984)
//   pos8     : u8  [1705984, 1956352)
//   ovfc     : int [1956352]
//   ovf      : int [1956416, 1964608)
//   Bf1      : s16 [1964608, 1980992)    32768 halfs (frag-ordered hi/lo)
//   Bf2      : s16 [1980992, 1997376)
//   slots    : int [1997376, 8397376)    N*64
//   xb       : u16 [8397376, 11597376)   N*64 bf16 = 6.4M halfs = 3.2M units
//   mean1    : f32 [11597376, 17997376)  N*64; region reused as p_bf after l1
//   h        : f32 [17997376, 30797376)  N*128
//   q        : f32 [30797376, 37197376)  N*64
// total 37,197,376 * 4B = 148.8 MB

__global__ __launch_bounds__(256) void init_kernel(int4* __restrict__ counts_r,
                                                   int* __restrict__ ovfc) {
    int i = blockIdx.x * blockDim.x + threadIdx.x;
    if (i < (8 * RSTRIDE) / 4) counts_r[i] = make_int4(0, 0, 0, 0);
    if (i == 0) *ovfc = 0;
}

// x (fp32) -> xb (bf16, RTN)
__global__ __launch_bounds__(256) void prep_x_kernel(const float4* __restrict__ x4,
                                                     ushort4* __restrict__ xb4) {
    int i = blockIdx.x * blockDim.x + threadIdx.x;
    if (i >= N_NODES * 16) return;
    float4 v = x4[i];
    ushort4 o;
    o.x = f2bf(v.x); o.y = f2bf(v.y); o.z = f2bf(v.z); o.w = f2bf(v.w);
    xb4[i] = o;
}

// Pre-split weights into MFMA-fragment-ordered bf16 hi/lo.
// Bf layout: [(c*4+kc)*2 + term][lane][j]  (512 halfs per chunk)
//   element (k,n): c=n>>4, kc=k>>5, lane=((k>>3)&3)<<4 | (n&15), j=k&7
__global__ __launch_bounds__(256) void prep_b_kernel(
        const float* __restrict__ W1l, const float* __restrict__ W1r,
        const float* __restrict__ W2l, const float* __restrict__ W2r,
        short* __restrict__ Bf1, short* __restrict__ Bf2) {
    int idx = blockIdx.x * blockDim.x + threadIdx.x;
    if (idx >= 32768) return;
    int g = idx >> 14;
    int e = idx & 16383;
    int k = e >> 7;
    int n = e & 127;
    float v;
    if (g == 0) v = (k < 64) ? W1l[k * 128 + n] : W1r[(k - 64) * 128 + n];
    else        v = (n < 64) ? W2l[k * 64 + n]  : W2r[k * 64 + (n - 64)];
    unsigned u = __float_as_uint(v);
    unsigned hb = u >> 16;
    float vh = __uint_as_float(hb << 16);
    unsigned lb = __float_as_uint(v - vh) >> 16;
    int c = n >> 4, kc = k >> 5;
    int lane = (((k >> 3) & 3) << 4) | (n & 15);
    int j = k & 7;
    short* base = g ? Bf2 : Bf1;
    base[((c * 4 + kc) * 2 + 0) * 512 + lane * 8 + j] = (short)hb;
    base[((c * 4 + kc) * 2 + 1) * 512 + lane * 8 + j] = (short)lb;
}

// Phase 1: replicated histogram (8 replicas, replica by edge-block ~ XCD).
__global__ __launch_bounds__(256) void hist_kernel(
        const int* __restrict__ ei, int* __restrict__ counts_r,
        unsigned char* __restrict__ pos8) {
    int e = blockIdx.x * blockDim.x + threadIdx.x;
    if (e >= N_EDGES) return;
    int d = ei[N_EDGES + e];
    int r = (e >> 8) & 7;
    int p = atomicAdd(&counts_r[r * RSTRIDE + d], 1);
    pos8[e] = (unsigned char)(p < 255 ? p : 255);
}

// Phase 2: per-node prefix over the 8 replicas.
__global__ __launch_bounds__(256) void scan_kernel(
        const int* __restrict__ counts_r, int* __restrict__ bases_r,
        int* __restrict__ counts) {
    int d = blockIdx.x * blockDim.x + threadIdx.x;
    if (d >= N_NODES) return;
    int base = 0;
#pragma unroll
    for (int r = 0; r < 8; ++r) {
        bases_r[r * RSTRIDE + d] = base;
        base += counts_r[r * RSTRIDE + d];
    }
    counts[d] = base;
}

// Phase 3: atomic-free slot fill; overflow funnel for deg>64.
__global__ __launch_bounds__(256) void fill_kernel(
        const int* __restrict__ ei, const unsigned char* __restrict__ pos8,
        const int* __restrict__ bases_r, int* __restrict__ slots,
        int* __restrict__ ovfc, int* __restrict__ ovf) {
    int e = blockIdx.x * blockDim.x + threadIdx.x;
    if (e >= N_EDGES) return;
    int s = ei[e];
    int d = ei[N_EDGES + e];
    int r = (e >> 8) & 7;
    int p8 = pos8[e];
    int pos = bases_r[r * RSTRIDE + d] + p8;
    if (p8 < 255 && pos < DEG_CAP) {
        slots[d * DEG_CAP + pos] = s;
    } else {
        int o = atomicAdd(ovfc, 1);
        if (o < OVF_CAP) { ovf[o * 2] = s; ovf[o * 2 + 1] = d; }
    }
}

// One wave per node, lane = feature. bf16 feature rows (128B), fp32 accum.
// Writes the MEAN (fp32).
__global__ __launch_bounds__(256) void gather_bf_kernel(
        const unsigned short* __restrict__ feat, const int* __restrict__ counts,
        const int* __restrict__ slots, float* __restrict__ agg) {
    int wid = blockIdx.x * 4 + (threadIdx.x >> 6);
    int f = threadIdx.x & 63;
    if (wid >= N_NODES) return;
    int deg = counts[wid];
    int dcap = min(deg, DEG_CAP);
    int ids = slots[wid * DEG_CAP + f];
    float sum = 0.f;
    int j = 0;
    for (; j + 8 <= dcap; j += 8) {
        int s0 = __shfl(ids, j + 0);
        int s1 = __shfl(ids, j + 1);
        int s2 = __shfl(ids, j + 2);
        int s3 = __shfl(ids, j + 3);
        int s4 = __shfl(ids, j + 4);
        int s5 = __shfl(ids, j + 5);
        int s6 = __shfl(ids, j + 6);
        int s7 = __shfl(ids, j + 7);
        unsigned short v0 = feat[s0 * 64 + f];
        unsigned short v1 = feat[s1 * 64 + f];
        unsigned short v2 = feat[s2 * 64 + f];
        unsigned short v3 = feat[s3 * 64 + f];
        unsigned short v4 = feat[s4 * 64 + f];
        unsigned short v5 = feat[s5 * 64 + f];
        unsigned short v6 = feat[s6 * 64 + f];
        unsigned short v7 = feat[s7 * 64 + f];
        sum += ((bf2f(v0) + bf2f(v1)) + (bf2f(v2) + bf2f(v3)))
             + ((bf2f(v4) + bf2f(v5)) + (bf2f(v6) + bf2f(v7)));
    }
    for (; j < dcap; ++j) {
        int s = __shfl(ids, j);
        sum += bf2f(feat[s * 64 + f]);
    }
    float inv = 1.0f / fmaxf((float)deg, 1.0f);
    agg[wid * 64 + f] = sum * inv;
}

// Layer-1 overflow: add x*inv into mean (fp32 x; overflow is ~never hit).
__global__ __launch_bounds__(64) void ovf_scatter_kernel(
        const float* __restrict__ feat, const int* __restrict__ ovf,
        const int* __restrict__ ovfc, const int* __restrict__ counts,
        float* __restrict__ agg) {
    int n = *ovfc;
    if (n > OVF_CAP) n = OVF_CAP;
    for (int idx = blockIdx.x; idx < n; idx += gridDim.x) {
        int s = ovf[idx * 2];
        int d = ovf[idx * 2 + 1];
        float inv = 1.0f / fmaxf((float)counts[d], 1.0f);
        atomicAdd(&agg[d * 64 + threadIdx.x], feat[s * 64 + threadIdx.x] * inv);
    }
}

// Layer 1 MFMA: h = relu( [mean|x] @ [W1l;W1r] + b1 )
// 32 rows/wave (2 row-tiles), 3-term split-bf16 16x16x32. No LDS/barriers.
__global__ __launch_bounds__(256) void l1_mfma_kernel(
        const float* __restrict__ mean1, const float* __restrict__ x,
        const short* __restrict__ Bf1, const float* __restrict__ b1,
        float* __restrict__ h) {
    const int w = threadIdx.x >> 6;
    const int l = threadIdx.x & 63;
    const int lane15 = l & 15;
    const int quad = l >> 4;
    const int rowBaseW = blockIdx.x * 128 + w * 32;

    bf16x8 ah[2][4], al[2][4];
#pragma unroll
    for (int rt = 0; rt < 2; ++rt) {
        const int row = rowBaseW + rt * 16 + lane15;
        const bool rv = row < N_NODES;
#pragma unroll
        for (int kc = 0; kc < 4; ++kc) {
            float4 v0 = make_float4(0.f, 0.f, 0.f, 0.f);
            float4 v1 = make_float4(0.f, 0.f, 0.f, 0.f);
            if (rv) {
                const float* src = (kc < 2)
                    ? (mean1 + row * 64 + kc * 32 + quad * 8)
                    : (x     + row * 64 + (kc - 2) * 32 + quad * 8);
                v0 = *(const float4*)src;
                v1 = *(const float4*)(src + 4);
            }
            float f[8] = {v0.x, v0.y, v0.z, v0.w, v1.x, v1.y, v1.z, v1.w};
#pragma unroll
            for (int j = 0; j < 8; ++j) {
                unsigned u = __float_as_uint(f[j]);
                unsigned hb = u >> 16;
                float fh = __uint_as_float(hb << 16);
                unsigned lb = __float_as_uint(f[j] - fh) >> 16;
                ah[rt][kc][j] = (short)hb;
                al[rt][kc][j] = (short)lb;
            }
        }
    }

    f32x4 acc[2][8];
#pragma unroll
    for (int rt = 0; rt < 2; ++rt)
#pragma unroll
        for (int c = 0; c < 8; ++c) acc[rt][c] = (f32x4){0.f, 0.f, 0.f, 0.f};

#pragma unroll
    for (int kc = 0; kc < 4; ++kc) {
#pragma unroll
        for (int c = 0; c < 8; ++c) {
            const short* bp = Bf1 + ((c * 4 + kc) * 2) * 512 + l * 8;
            bf16x8 bh = *(const bf16x8*)bp;
            bf16x8 bl = *(const bf16x8*)(bp + 512);
#pragma unroll
            for (int rt = 0; rt < 2; ++rt) {
                acc[rt][c] = __builtin_amdgcn_mfma_f32_16x16x32_bf16(ah[rt][kc], bh, acc[rt][c], 0, 0, 0);
                acc[rt][c] = __builtin_amdgcn_mfma_f32_16x16x32_bf16(al[rt][kc], bh, acc[rt][c], 0, 0, 0);
                acc[rt][c] = __builtin_amdgcn_mfma_f32_16x16x32_bf16(ah[rt][kc], bl, acc[rt][c], 0, 0, 0);
            }
        }
    }

    // C layout: col = c*16 + lane15, row = quad*4 + i
#pragma unroll
    for (int rt = 0; rt < 2; ++rt) {
        const int rbase = rowBaseW + rt * 16 + quad * 4;
#pragma unroll
        for (int c = 0; c < 8; ++c) {
            float bias = b1[c * 16 + lane15];
#pragma unroll
            for (int i = 0; i < 4; ++i) {
                int r = rbase + i;
                if (r < N_NODES)
                    h[r * 128 + c * 16 + lane15] = fmaxf(acc[rt][c][i] + bias, 0.f);
            }
        }
    }
}

// Layer 2 MFMA: p(bf16) = h @ W2l ; q(fp32) = h @ W2r + b2
__global__ __launch_bounds__(256) void l2_mfma_kernel(
        const float* __restrict__ h, const short* __restrict__ Bf2,
        const float* __restrict__ b2,
        unsigned short* __restrict__ p_bf, float* __restrict__ q) {
    const int w = threadIdx.x >> 6;
    const int l = threadIdx.x & 63;
    const int lane15 = l & 15;
    const int quad = l >> 4;
    const int rowBaseW = blockIdx.x * 128 + w * 32;

    bf16x8 ah[2][4], al[2][4];
#pragma unroll
    for (int rt = 0; rt < 2; ++rt) {
        const int row = rowBaseW + rt * 16 + lane15;
        const bool rv = row < N_NODES;
#pragma unroll
        for (int kc = 0; kc < 4; ++kc) {
            float4 v0 = make_float4(0.f, 0.f, 0.f, 0.f);
            float4 v1 = make_float4(0.f, 0.f, 0.f, 0.f);
            if (rv) {
                const float* src = h + row * 128 + kc * 32 + quad * 8;
                v0 = *(const float4*)src;
                v1 = *(const float4*)(src + 4);
            }
            float f[8] = {v0.x, v0.y, v0.z, v0.w, v1.x, v1.y, v1.z, v1.w};
#pragma unroll
            for (int j = 0; j < 8; ++j) {
                unsigned u = __float_as_uint(f[j]);
                unsigned hb = u >> 16;
                float fh = __uint_as_float(hb << 16);
                unsigned lb = __float_as_uint(f[j] - fh) >> 16;
                ah[rt][kc][j] = (short)hb;
                al[rt][kc][j] = (short)lb;
            }
        }
    }

    f32x4 acc[2][8];
#pragma unroll
    for (int rt = 0; rt < 2; ++rt)
#pragma unroll
        for (int c = 0; c < 8; ++c) acc[rt][c] = (f32x4){0.f, 0.f, 0.f, 0.f};

#pragma unroll
    for (int kc = 0; kc < 4; ++kc) {
#pragma unroll
        for (int c = 0; c < 8; ++c) {
            const short* bp = Bf2 + ((c * 4 + kc) * 2) * 512 + l * 8;
            bf16x8 bh = *(const bf16x8*)bp;
            bf16x8 bl = *(const bf16x8*)(bp + 512);
#pragma unroll
            for (int rt = 0; rt < 2; ++rt) {
                acc[rt][c] = __builtin_amdgcn_mfma_f32_16x16x32_bf16(ah[rt][kc], bh, acc[rt][c], 0, 0, 0);
                acc[rt][c] = __builtin_amdgcn_mfma_f32_16x16x32_bf16(al[rt][kc], bh, acc[rt][c], 0, 0, 0);
                acc[rt][c] = __builtin_amdgcn_mfma_f32_16x16x32_bf16(ah[rt][kc], bl, acc[rt][c], 0, 0, 0);
            }
        }
    }

#pragma unroll
    for (int rt = 0; rt < 2; ++rt) {
        const int rbase = rowBaseW + rt * 16 + quad * 4;
#pragma unroll
        for (int c = 0; c < 8; ++c) {
            if (c < 4) {
#pragma unroll
                for (int i = 0; i < 4; ++i) {
                    int r = rbase + i;
                    if (r < N_NODES)
                        p_bf[r * 64 + c * 16 + lane15] = f2bf(acc[rt][c][i]);
                }
            } else {
                float bias = b2[(c - 4) * 16 + lane15];
#pragma unroll
                for (int i = 0; i < 4; ++i) {
                    int r = rbase + i;
                    if (r < N_NODES)
                        q[r * 64 + (c - 4) * 16 + lane15] = acc[rt][c][i] + bias;
                }
            }
        }
    }
}

// Fused layer-2 aggregation + epilogue: out = mean(p_bf[nbrs]) + q
__global__ __launch_bounds__(256) void gather_final_kernel(
        const unsigned short* __restrict__ p, const int* __restrict__ counts,
        const int* __restrict__ slots, const float* __restrict__ q,
        float* __restrict__ out) {
    int wid = blockIdx.x * 4 + (threadIdx.x >> 6);
    int f = threadIdx.x & 63;
    if (wid >= N_NODES) return;
    int deg = counts[wid];
    int dcap = min(deg, DEG_CAP);
    int ids = slots[wid * DEG_CAP + f];
    float sum = 0.f;
    int j = 0;
    for (; j + 8 <= dcap; j += 8) {
        int s0 = __shfl(ids, j + 0);
        int s1 = __shfl(ids, j + 1);
        int s2 = __shfl(ids, j + 2);
        int s3 = __shfl(ids, j + 3);
        int s4 = __shfl(ids, j + 4);
        int s5 = __shfl(ids, j + 5);
        int s6 = __shfl(ids, j + 6);
        int s7 = __shfl(ids, j + 7);
        unsigned short v0 = p[s0 * 64 + f];
        unsigned short v1 = p[s1 * 64 + f];
        unsigned short v2 = p[s2 * 64 + f];
        unsigned short v3 = p[s3 * 64 + f];
        unsigned short v4 = p[s4 * 64 + f];
        unsigned short v5 = p[s5 * 64 + f];
        unsigned short v6 = p[s6 * 64 + f];
        unsigned short v7 = p[s7 * 64 + f];
        sum += ((bf2f(v0) + bf2f(v1)) + (bf2f(v2) + bf2f(v3)))
             + ((bf2f(v4) + bf2f(v5)) + (bf2f(v6) + bf2f(v7)));
    }
    for (; j < dcap; ++j) {
        int s = __shfl(ids, j);
        sum += bf2f(p[s * 64 + f]);
    }
    float inv = 1.0f / fmaxf((float)deg, 1.0f);
    out[wid * 64 + f] = sum * inv + q[wid * 64 + f];
}

// Layer-2 overflow fix-up (additive).
__global__ __launch_bounds__(64) void ovf_fixup_kernel(
        const unsigned short* __restrict__ p, const int* __restrict__ ovf,
        const int* __restrict__ ovfc, const int* __restrict__ counts,
        float* __restrict__ out) {
    int n = *ovfc;
    if (n > OVF_CAP) n = OVF_CAP;
    for (int idx = blockIdx.x; idx < n; idx += gridDim.x) {
        int s = ovf[idx * 2];
        int d = ovf[idx * 2 + 1];
        float inv = 1.0f / fmaxf((float)counts[d], 1.0f);
        atomicAdd(&out[d * 64 + threadIdx.x],
                  bf2f(p[s * 64 + threadIdx.x]) * inv);
    }
}

extern "C" void kernel_launch(void* const* d_in, const int* in_sizes, int n_in,
                              void* d_out, int out_size, void* d_ws, size_t ws_size,
                              hipStream_t stream) {
    const float* x   = (const float*)d_in[0];
    const float* W1l = (const float*)d_in[1];
    const float* W1r = (const float*)d_in[2];
    const float* b1  = (const float*)d_in[3];
    const float* W2l = (const float*)d_in[4];
    const float* W2r = (const float*)d_in[5];
    const float* b2  = (const float*)d_in[6];
    const int*   ei  = (const int*)d_in[7];

    int*   wsi      = (int*)d_ws;
    float* wsf      = (float*)d_ws;
    int*   counts_r = wsi;
    int*   bases_r  = wsi + 802816;
    int*   counts   = wsi + 1605632;
    unsigned char* pos8 = (unsigned char*)(wsi + 1705984);
    int*   ovfc     = wsi + 1956352;
    int*   ovf      = wsi + 1956416;
    short* Bf1      = (short*)(wsi + 1964608);
    short* Bf2      = (short*)(wsi + 1980992);
    int*   slots    = wsi + 1997376;
    unsigned short* xb = (unsigned short*)(wsi + 8397376);   // 3.2M units
    float* mean1    = wsf + 11597376;
    unsigned short* p_bf = (unsigned short*)(wsf + 11597376);  // reuse after l1
    float* h        = wsf + 17997376;
    float* q        = wsf + 30797376;
    float* out      = (float*)d_out;

    init_kernel<<<(8 * RSTRIDE / 4 + 255) / 256, 256, 0, stream>>>(
        (int4*)counts_r, ovfc);
    prep_b_kernel<<<128, 256, 0, stream>>>(W1l, W1r, W2l, W2r, Bf1, Bf2);
    prep_x_kernel<<<(N_NODES * 16 + 255) / 256, 256, 0, stream>>>(
        (const float4*)x, (ushort4*)xb);
    hist_kernel<<<(N_EDGES + 255) / 256, 256, 0, stream>>>(ei, counts_r, pos8);
    scan_kernel<<<(N_NODES + 255) / 256, 256, 0, stream>>>(counts_r, bases_r, counts);
    fill_kernel<<<(N_EDGES + 255) / 256, 256, 0, stream>>>(
        ei, pos8, bases_r, slots, ovfc, ovf);

    // layer-1 aggregation -> mean (bf16 rows), + overflow
    gather_bf_kernel<<<(N_NODES + 3) / 4, 256, 0, stream>>>(xb, counts, slots, mean1);
    ovf_scatter_kernel<<<64, 64, 0, stream>>>(x, ovf, ovfc, counts, mean1);

    // h = relu([mean|x] @ [W1l;W1r] + b1)
    l1_mfma_kernel<<<(N_NODES + 127) / 128, 256, 0, stream>>>(
        mean1, x, Bf1, b1, h);
    // p(bf16) = h @ W2l ; q = h @ W2r + b2   (p_bf overwrites mean1)
    l2_mfma_kernel<<<(N_NODES + 127) / 128, 256, 0, stream>>>(h, Bf2, b2, p_bf, q);

    // fused layer-2 aggregation + epilogue, then overflow fix-up
    gather_final_kernel<<<(N_NODES + 3) / 4, 256, 0, stream>>>(
        p_bf, counts, slots, q, out);
    ovf_fixup_kernel<<<64, 64, 0, stream>>>(p_bf, ovf, ovfc, counts, out);
}

// Round 7
// 288.229 us; speedup vs baseline: 2.4039x; 1.0632x over previous
//
#include <hip/hip_runtime.h>

#define N_NODES 100000
#define N_EDGES 1000000
#define DEG_CAP 64
#define OVF_CAP 4096
#define RSTRIDE 100352   // N_NODES rounded up to 512

typedef __attribute__((ext_vector_type(8))) short bf16x8;
typedef __attribute__((ext_vector_type(4))) float f32x4;

__device__ __forceinline__ unsigned short f2bf(float f) {
    unsigned u = __float_as_uint(f);
    return (unsigned short)((u + 0x7FFF + ((u >> 16) & 1)) >> 16);
}
__device__ __forceinline__ float bf2f(unsigned short b) {
    return __uint_as_float(((unsigned)b) << 16);
}
__device__ __forceinline__ float bflo(unsigned u) {   // low bf16 of a dword
    return __uint_as_float(u << 16);
}
__device__ __forceinline__ float bfhi(unsigned u) {   // high bf16 of a dword
    return __uint_as_float(u & 0xffff0000u);
}

// ws layout (4B units):
//   counts_r : int [0,        802816)    8 replicas x RSTRIDE
//   bases_r  : int [802816,  1605632)
//   counts   : int [1605632, 1705984)
//   pos8     : u8  [1705984, 1956352)
//   ovfc     : int [1956352]
//   ovf      : int [1956416, 1964608)
//   Bf1      : s16 [1964608, 1980992)    32768 halfs (frag-ordered hi/lo)
//   Bf2      : s16 [1980992, 1997376)
//   slots    : int [1997376, 8397376)    N*64
//   xb       : u16 [8397376, 11597376)   N*64 bf16 = 6.4M halfs = 3.2M units
//   mean1    : f32 [11597376, 17997376)  N*64; region reused as p_bf after l1
//   h        : f32 [17997376, 30797376)  N*128
//   q        : f32 [30797376, 37197376)  N*64
// total 37,197,376 * 4B = 148.8 MB

__global__ __launch_bounds__(256) void init_kernel(int4* __restrict__ counts_r,
                                                   int* __restrict__ ovfc) {
    int i = blockIdx.x * blockDim.x + threadIdx.x;
    if (i < (8 * RSTRIDE) / 4) counts_r[i] = make_int4(0, 0, 0, 0);
    if (i == 0) *ovfc = 0;
}

// x (fp32) -> xb (bf16, RTN)
__global__ __launch_bounds__(256) void prep_x_kernel(const float4* __restrict__ x4,
                                                     ushort4* __restrict__ xb4) {
    int i = blockIdx.x * blockDim.x + threadIdx.x;
    if (i >= N_NODES * 16) return;
    float4 v = x4[i];
    ushort4 o;
    o.x = f2bf(v.x); o.y = f2bf(v.y); o.z = f2bf(v.z); o.w = f2bf(v.w);
    xb4[i] = o;
}

// Pre-split weights into MFMA-fragment-ordered bf16 hi/lo.
// Bf layout: [(c*4+kc)*2 + term][lane][j]  (512 halfs per chunk)
//   element (k,n): c=n>>4, kc=k>>5, lane=((k>>3)&3)<<4 | (n&15), j=k&7
__global__ __launch_bounds__(256) void prep_b_kernel(
        const float* __restrict__ W1l, const float* __restrict__ W1r,
        const float* __restrict__ W2l, const float* __restrict__ W2r,
        short* __restrict__ Bf1, short* __restrict__ Bf2) {
    int idx = blockIdx.x * blockDim.x + threadIdx.x;
    if (idx >= 32768) return;
    int g = idx >> 14;
    int e = idx & 16383;
    int k = e >> 7;
    int n = e & 127;
    float v;
    if (g == 0) v = (k < 64) ? W1l[k * 128 + n] : W1r[(k - 64) * 128 + n];
    else        v = (n < 64) ? W2l[k * 64 + n]  : W2r[k * 64 + (n - 64)];
    unsigned u = __float_as_uint(v);
    unsigned hb = u >> 16;
    float vh = __uint_as_float(hb << 16);
    unsigned lb = __float_as_uint(v - vh) >> 16;
    int c = n >> 4, kc = k >> 5;
    int lane = (((k >> 3) & 3) << 4) | (n & 15);
    int j = k & 7;
    short* base = g ? Bf2 : Bf1;
    base[((c * 4 + kc) * 2 + 0) * 512 + lane * 8 + j] = (short)hb;
    base[((c * 4 + kc) * 2 + 1) * 512 + lane * 8 + j] = (short)lb;
}

// Phase 1: replicated histogram (8 replicas, replica by edge-block ~ XCD).
__global__ __launch_bounds__(256) void hist_kernel(
        const int* __restrict__ ei, int* __restrict__ counts_r,
        unsigned char* __restrict__ pos8) {
    int e = blockIdx.x * blockDim.x + threadIdx.x;
    if (e >= N_EDGES) return;
    int d = ei[N_EDGES + e];
    int r = (e >> 8) & 7;
    int p = atomicAdd(&counts_r[r * RSTRIDE + d], 1);
    pos8[e] = (unsigned char)(p < 255 ? p : 255);
}

// Phase 2: per-node prefix over the 8 replicas.
__global__ __launch_bounds__(256) void scan_kernel(
        const int* __restrict__ counts_r, int* __restrict__ bases_r,
        int* __restrict__ counts) {
    int d = blockIdx.x * blockDim.x + threadIdx.x;
    if (d >= N_NODES) return;
    int base = 0;
#pragma unroll
    for (int r = 0; r < 8; ++r) {
        bases_r[r * RSTRIDE + d] = base;
        base += counts_r[r * RSTRIDE + d];
    }
    counts[d] = base;
}

// Phase 3: atomic-free slot fill; overflow funnel for deg>64.
__global__ __launch_bounds__(256) void fill_kernel(
        const int* __restrict__ ei, const unsigned char* __restrict__ pos8,
        const int* __restrict__ bases_r, int* __restrict__ slots,
        int* __restrict__ ovfc, int* __restrict__ ovf) {
    int e = blockIdx.x * blockDim.x + threadIdx.x;
    if (e >= N_EDGES) return;
    int s = ei[e];
    int d = ei[N_EDGES + e];
    int r = (e >> 8) & 7;
    int p8 = pos8[e];
    int pos = bases_r[r * RSTRIDE + d] + p8;
    if (p8 < 255 && pos < DEG_CAP) {
        slots[d * DEG_CAP + pos] = s;
    } else {
        int o = atomicAdd(ovfc, 1);
        if (o < OVF_CAP) { ovf[o * 2] = s; ovf[o * 2 + 1] = d; }
    }
}

// One wave per node. Lane l: neighbor subgroup l>>4, features (l&15)*4..+3.
// One dwordx2 load covers 4 bf16 features of one neighbor; 4 subgroups ->
// 4 neighbor rows per load instruction. Butterfly-reduce across subgroups.
// Writes the MEAN (fp32).
__global__ __launch_bounds__(256) void gather_bf_kernel(
        const unsigned short* __restrict__ feat, const int* __restrict__ counts,
        const int* __restrict__ slots, float* __restrict__ agg) {
    int wid = blockIdx.x * 4 + (threadIdx.x >> 6);
    int l = threadIdx.x & 63;
    if (wid >= N_NODES) return;
    int deg = counts[wid];
    int dcap = min(deg, DEG_CAP);
    int ids = slots[wid * DEG_CAP + l];
    const int grp = l >> 4;
    const int fb = (l & 15) * 4;
    float s0 = 0.f, s1 = 0.f, s2 = 0.f, s3 = 0.f;
    int j = 0;
    for (; j + 8 <= dcap; j += 8) {   // grp<=3 -> both neighbors in-range
        int sA = __shfl(ids, j + grp);
        int sB = __shfl(ids, j + 4 + grp);
        uint2 uA = *(const uint2*)(feat + sA * 64 + fb);
        uint2 uB = *(const uint2*)(feat + sB * 64 + fb);
        s0 += bflo(uA.x) + bflo(uB.x);
        s1 += bfhi(uA.x) + bfhi(uB.x);
        s2 += bflo(uA.y) + bflo(uB.y);
        s3 += bfhi(uA.y) + bfhi(uB.y);
    }
    for (; j < dcap; j += 4) {
        int nb = j + grp;
        bool v = nb < dcap;
        int s = __shfl(ids, v ? nb : 0);
        uint2 u = *(const uint2*)(feat + s * 64 + fb);
        if (v) {
            s0 += bflo(u.x);
            s1 += bfhi(u.x);
            s2 += bflo(u.y);
            s3 += bfhi(u.y);
        }
    }
    // reduce across the 4 subgroups (lanes ^16, ^32)
    s0 += __shfl_xor(s0, 16); s0 += __shfl_xor(s0, 32);
    s1 += __shfl_xor(s1, 16); s1 += __shfl_xor(s1, 32);
    s2 += __shfl_xor(s2, 16); s2 += __shfl_xor(s2, 32);
    s3 += __shfl_xor(s3, 16); s3 += __shfl_xor(s3, 32);
    if (l < 16) {
        float inv = 1.0f / fmaxf((float)deg, 1.0f);
        *(float4*)&agg[wid * 64 + fb] =
            make_float4(s0 * inv, s1 * inv, s2 * inv, s3 * inv);
    }
}

// Layer-1 overflow: add x*inv into mean (fp32 x; overflow is ~never hit).
__global__ __launch_bounds__(64) void ovf_scatter_kernel(
        const float* __restrict__ feat, const int* __restrict__ ovf,
        const int* __restrict__ ovfc, const int* __restrict__ counts,
        float* __restrict__ agg) {
    int n = *ovfc;
    if (n > OVF_CAP) n = OVF_CAP;
    for (int idx = blockIdx.x; idx < n; idx += gridDim.x) {
        int s = ovf[idx * 2];
        int d = ovf[idx * 2 + 1];
        float inv = 1.0f / fmaxf((float)counts[d], 1.0f);
        atomicAdd(&agg[d * 64 + threadIdx.x], feat[s * 64 + threadIdx.x] * inv);
    }
}

// Layer 1 MFMA: h = relu( [mean|x] @ [W1l;W1r] + b1 )
// 32 rows/wave (2 row-tiles), 3-term split-bf16 16x16x32. No LDS/barriers.
__global__ __launch_bounds__(256) void l1_mfma_kernel(
        const float* __restrict__ mean1, const float* __restrict__ x,
        const short* __restrict__ Bf1, const float* __restrict__ b1,
        float* __restrict__ h) {
    const int w = threadIdx.x >> 6;
    const int l = threadIdx.x & 63;
    const int lane15 = l & 15;
    const int quad = l >> 4;
    const int rowBaseW = blockIdx.x * 128 + w * 32;

    bf16x8 ah[2][4], al[2][4];
#pragma unroll
    for (int rt = 0; rt < 2; ++rt) {
        const int row = rowBaseW + rt * 16 + lane15;
        const bool rv = row < N_NODES;
#pragma unroll
        for (int kc = 0; kc < 4; ++kc) {
            float4 v0 = make_float4(0.f, 0.f, 0.f, 0.f);
            float4 v1 = make_float4(0.f, 0.f, 0.f, 0.f);
            if (rv) {
                const float* src = (kc < 2)
                    ? (mean1 + row * 64 + kc * 32 + quad * 8)
                    : (x     + row * 64 + (kc - 2) * 32 + quad * 8);
                v0 = *(const float4*)src;
                v1 = *(const float4*)(src + 4);
            }
            float f[8] = {v0.x, v0.y, v0.z, v0.w, v1.x, v1.y, v1.z, v1.w};
#pragma unroll
            for (int j = 0; j < 8; ++j) {
                unsigned u = __float_as_uint(f[j]);
                unsigned hb = u >> 16;
                float fh = __uint_as_float(hb << 16);
                unsigned lb = __float_as_uint(f[j] - fh) >> 16;
                ah[rt][kc][j] = (short)hb;
                al[rt][kc][j] = (short)lb;
            }
        }
    }

    f32x4 acc[2][8];
#pragma unroll
    for (int rt = 0; rt < 2; ++rt)
#pragma unroll
        for (int c = 0; c < 8; ++c) acc[rt][c] = (f32x4){0.f, 0.f, 0.f, 0.f};

#pragma unroll
    for (int kc = 0; kc < 4; ++kc) {
#pragma unroll
        for (int c = 0; c < 8; ++c) {
            const short* bp = Bf1 + ((c * 4 + kc) * 2) * 512 + l * 8;
            bf16x8 bh = *(const bf16x8*)bp;
            bf16x8 bl = *(const bf16x8*)(bp + 512);
#pragma unroll
            for (int rt = 0; rt < 2; ++rt) {
                acc[rt][c] = __builtin_amdgcn_mfma_f32_16x16x32_bf16(ah[rt][kc], bh, acc[rt][c], 0, 0, 0);
                acc[rt][c] = __builtin_amdgcn_mfma_f32_16x16x32_bf16(al[rt][kc], bh, acc[rt][c], 0, 0, 0);
                acc[rt][c] = __builtin_amdgcn_mfma_f32_16x16x32_bf16(ah[rt][kc], bl, acc[rt][c], 0, 0, 0);
            }
        }
    }

    // C layout: col = c*16 + lane15, row = quad*4 + i
#pragma unroll
    for (int rt = 0; rt < 2; ++rt) {
        const int rbase = rowBaseW + rt * 16 + quad * 4;
#pragma unroll
        for (int c = 0; c < 8; ++c) {
            float bias = b1[c * 16 + lane15];
#pragma unroll
            for (int i = 0; i < 4; ++i) {
                int r = rbase + i;
                if (r < N_NODES)
                    h[r * 128 + c * 16 + lane15] = fmaxf(acc[rt][c][i] + bias, 0.f);
            }
        }
    }
}

// Layer 2 MFMA: p(bf16) = h @ W2l ; q(fp32) = h @ W2r + b2
__global__ __launch_bounds__(256) void l2_mfma_kernel(
        const float* __restrict__ h, const short* __restrict__ Bf2,
        const float* __restrict__ b2,
        unsigned short* __restrict__ p_bf, float* __restrict__ q) {
    const int w = threadIdx.x >> 6;
    const int l = threadIdx.x & 63;
    const int lane15 = l & 15;
    const int quad = l >> 4;
    const int rowBaseW = blockIdx.x * 128 + w * 32;

    bf16x8 ah[2][4], al[2][4];
#pragma unroll
    for (int rt = 0; rt < 2; ++rt) {
        const int row = rowBaseW + rt * 16 + lane15;
        const bool rv = row < N_NODES;
#pragma unroll
        for (int kc = 0; kc < 4; ++kc) {
            float4 v0 = make_float4(0.f, 0.f, 0.f, 0.f);
            float4 v1 = make_float4(0.f, 0.f, 0.f, 0.f);
            if (rv) {
                const float* src = h + row * 128 + kc * 32 + quad * 8;
                v0 = *(const float4*)src;
                v1 = *(const float4*)(src + 4);
            }
            float f[8] = {v0.x, v0.y, v0.z, v0.w, v1.x, v1.y, v1.z, v1.w};
#pragma unroll
            for (int j = 0; j < 8; ++j) {
                unsigned u = __float_as_uint(f[j]);
                unsigned hb = u >> 16;
                float fh = __uint_as_float(hb << 16);
                unsigned lb = __float_as_uint(f[j] - fh) >> 16;
                ah[rt][kc][j] = (short)hb;
                al[rt][kc][j] = (short)lb;
            }
        }
    }

    f32x4 acc[2][8];
#pragma unroll
    for (int rt = 0; rt < 2; ++rt)
#pragma unroll
        for (int c = 0; c < 8; ++c) acc[rt][c] = (f32x4){0.f, 0.f, 0.f, 0.f};

#pragma unroll
    for (int kc = 0; kc < 4; ++kc) {
#pragma unroll
        for (int c = 0; c < 8; ++c) {
            const short* bp = Bf2 + ((c * 4 + kc) * 2) * 512 + l * 8;
            bf16x8 bh = *(const bf16x8*)bp;
            bf16x8 bl = *(const bf16x8*)(bp + 512);
#pragma unroll
            for (int rt = 0; rt < 2; ++rt) {
                acc[rt][c] = __builtin_amdgcn_mfma_f32_16x16x32_bf16(ah[rt][kc], bh, acc[rt][c], 0, 0, 0);
                acc[rt][c] = __builtin_amdgcn_mfma_f32_16x16x32_bf16(al[rt][kc], bh, acc[rt][c], 0, 0, 0);
                acc[rt][c] = __builtin_amdgcn_mfma_f32_16x16x32_bf16(ah[rt][kc], bl, acc[rt][c], 0, 0, 0);
            }
        }
    }

#pragma unroll
    for (int rt = 0; rt < 2; ++rt) {
        const int rbase = rowBaseW + rt * 16 + quad * 4;
#pragma unroll
        for (int c = 0; c < 8; ++c) {
            if (c < 4) {
#pragma unroll
                for (int i = 0; i < 4; ++i) {
                    int r = rbase + i;
                    if (r < N_NODES)
                        p_bf[r * 64 + c * 16 + lane15] = f2bf(acc[rt][c][i]);
                }
            } else {
                float bias = b2[(c - 4) * 16 + lane15];
#pragma unroll
                for (int i = 0; i < 4; ++i) {
                    int r = rbase + i;
                    if (r < N_NODES)
                        q[r * 64 + (c - 4) * 16 + lane15] = acc[rt][c][i] + bias;
                }
            }
        }
    }
}

// Fused layer-2 aggregation + epilogue: out = mean(p_bf[nbrs]) + q
// Same 4-neighbors-per-load structure as gather_bf_kernel.
__global__ __launch_bounds__(256) void gather_final_kernel(
        const unsigned short* __restrict__ p, const int* __restrict__ counts,
        const int* __restrict__ slots, const float* __restrict__ q,
        float* __restrict__ out) {
    int wid = blockIdx.x * 4 + (threadIdx.x >> 6);
    int l = threadIdx.x & 63;
    if (wid >= N_NODES) return;
    int deg = counts[wid];
    int dcap = min(deg, DEG_CAP);
    int ids = slots[wid * DEG_CAP + l];
    const int grp = l >> 4;
    const int fb = (l & 15) * 4;
    float s0 = 0.f, s1 = 0.f, s2 = 0.f, s3 = 0.f;
    int j = 0;
    for (; j + 8 <= dcap; j += 8) {
        int sA = __shfl(ids, j + grp);
        int sB = __shfl(ids, j + 4 + grp);
        uint2 uA = *(const uint2*)(p + sA * 64 + fb);
        uint2 uB = *(const uint2*)(p + sB * 64 + fb);
        s0 += bflo(uA.x) + bflo(uB.x);
        s1 += bfhi(uA.x) + bfhi(uB.x);
        s2 += bflo(uA.y) + bflo(uB.y);
        s3 += bfhi(uA.y) + bfhi(uB.y);
    }
    for (; j < dcap; j += 4) {
        int nb = j + grp;
        bool v = nb < dcap;
        int s = __shfl(ids, v ? nb : 0);
        uint2 u = *(const uint2*)(p + s * 64 + fb);
        if (v) {
            s0 += bflo(u.x);
            s1 += bfhi(u.x);
            s2 += bflo(u.y);
            s3 += bfhi(u.y);
        }
    }
    s0 += __shfl_xor(s0, 16); s0 += __shfl_xor(s0, 32);
    s1 += __shfl_xor(s1, 16); s1 += __shfl_xor(s1, 32);
    s2 += __shfl_xor(s2, 16); s2 += __shfl_xor(s2, 32);
    s3 += __shfl_xor(s3, 16); s3 += __shfl_xor(s3, 32);
    if (l < 16) {
        float inv = 1.0f / fmaxf((float)deg, 1.0f);
        float4 qv = *(const float4*)&q[wid * 64 + fb];
        *(float4*)&out[wid * 64 + fb] =
            make_float4(s0 * inv + qv.x, s1 * inv + qv.y,
                        s2 * inv + qv.z, s3 * inv + qv.w);
    }
}

// Layer-2 overflow fix-up (additive).
__global__ __launch_bounds__(64) void ovf_fixup_kernel(
        const unsigned short* __restrict__ p, const int* __restrict__ ovf,
        const int* __restrict__ ovfc, const int* __restrict__ counts,
        float* __restrict__ out) {
    int n = *ovfc;
    if (n > OVF_CAP) n = OVF_CAP;
    for (int idx = blockIdx.x; idx < n; idx += gridDim.x) {
        int s = ovf[idx * 2];
        int d = ovf[idx * 2 + 1];
        float inv = 1.0f / fmaxf((float)counts[d], 1.0f);
        atomicAdd(&out[d * 64 + threadIdx.x],
                  bf2f(p[s * 64 + threadIdx.x]) * inv);
    }
}

extern "C" void kernel_launch(void* const* d_in, const int* in_sizes, int n_in,
                              void* d_out, int out_size, void* d_ws, size_t ws_size,
                              hipStream_t stream) {
    const float* x   = (const float*)d_in[0];
    const float* W1l = (const float*)d_in[1];
    const float* W1r = (const float*)d_in[2];
    const float* b1  = (const float*)d_in[3];
    const float* W2l = (const float*)d_in[4];
    const float* W2r = (const float*)d_in[5];
    const float* b2  = (const float*)d_in[6];
    const int*   ei  = (const int*)d_in[7];

    int*   wsi      = (int*)d_ws;
    float* wsf      = (float*)d_ws;
    int*   counts_r = wsi;
    int*   bases_r  = wsi + 802816;
    int*   counts   = wsi + 1605632;
    unsigned char* pos8 = (unsigned char*)(wsi + 1705984);
    int*   ovfc     = wsi + 1956352;
    int*   ovf      = wsi + 1956416;
    short* Bf1      = (short*)(wsi + 1964608);
    short* Bf2      = (short*)(wsi + 1980992);
    int*   slots    = wsi + 1997376;
    unsigned short* xb = (unsigned short*)(wsi + 8397376);   // 3.2M units
    float* mean1    = wsf + 11597376;
    unsigned short* p_bf = (unsigned short*)(wsf + 11597376);  // reuse after l1
    float* h        = wsf + 17997376;
    float* q        = wsf + 30797376;
    float* out      = (float*)d_out;

    init_kernel<<<(8 * RSTRIDE / 4 + 255) / 256, 256, 0, stream>>>(
        (int4*)counts_r, ovfc);
    prep_b_kernel<<<128, 256, 0, stream>>>(W1l, W1r, W2l, W2r, Bf1, Bf2);
    prep_x_kernel<<<(N_NODES * 16 + 255) / 256, 256, 0, stream>>>(
        (const float4*)x, (ushort4*)xb);
    hist_kernel<<<(N_EDGES + 255) / 256, 256, 0, stream>>>(ei, counts_r, pos8);
    scan_kernel<<<(N_NODES + 255) / 256, 256, 0, stream>>>(counts_r, bases_r, counts);
    fill_kernel<<<(N_EDGES + 255) / 256, 256, 0, stream>>>(
        ei, pos8, bases_r, slots, ovfc, ovf);

    // layer-1 aggregation -> mean (bf16 rows), + overflow
    gather_bf_kernel<<<(N_NODES + 3) / 4, 256, 0, stream>>>(xb, counts, slots, mean1);
    ovf_scatter_kernel<<<64, 64, 0, stream>>>(x, ovf, ovfc, counts, mean1);

    // h = relu([mean|x] @ [W1l;W1r] + b1)
    l1_mfma_kernel<<<(N_NODES + 127) / 128, 256, 0, stream>>>(
        mean1, x, Bf1, b1, h);
    // p(bf16) = h @ W2l ; q = h @ W2r + b2   (p_bf overwrites mean1)
    l2_mfma_kernel<<<(N_NODES + 127) / 128, 256, 0, stream>>>(h, Bf2, b2, p_bf, q);

    // fused layer-2 aggregation + epilogue, then overflow fix-up
    gather_final_kernel<<<(N_NODES + 3) / 4, 256, 0, stream>>>(
        p_bf, counts, slots, q, out);
    ovf_fixup_kernel<<<64, 64, 0, stream>>>(p_bf, ovf, ovfc, counts, out);
}

// Round 8
// 287.376 us; speedup vs baseline: 2.4111x; 1.0030x over previous
//
#include <hip/hip_runtime.h>

#define N_NODES 100000
#define N_EDGES 1000000
#define DEG_CAP 64
#define OVF_CAP 4096
#define RSTRIDE 100352   // N_NODES rounded up to 512

typedef __attribute__((ext_vector_type(8))) short bf16x8;
typedef __attribute__((ext_vector_type(4))) float f32x4;

__device__ __forceinline__ unsigned short f2bf(float f) {
    unsigned u = __float_as_uint(f);
    return (unsigned short)((u + 0x7FFF + ((u >> 16) & 1)) >> 16);
}
__device__ __forceinline__ float bf2f(unsigned short b) {
    return __uint_as_float(((unsigned)b) << 16);
}
__device__ __forceinline__ float bflo(unsigned u) {   // low bf16 of a dword
    return __uint_as_float(u << 16);
}
__device__ __forceinline__ float bfhi(unsigned u) {   // high bf16 of a dword
    return __uint_as_float(u & 0xffff0000u);
}

// ws layout (4B units):
//   counts_r : int [0,        802816)    8 replicas x RSTRIDE
//   bases_r  : int [802816,  1605632)
//   counts   : int [1605632, 1705984)
//   pos8     : u8  [1705984, 1956352)
//   ovfc     : int [1956352]
//   ovf      : int [1956416, 1964608)
//   Bf1      : s16 [1964608, 1980992)    32768 halfs (frag-ordered hi/lo)
//   Bf2      : s16 [1980992, 1997376)
//   slots    : int [1997376, 8397376)    N*64
//   xb       : u16 [8397376, 11597376)   N*64 bf16 = 6.4M halfs = 3.2M units
//   mean1    : f32 [11597376, 17997376)  N*64; region reused as p_bf after l1
//   h        : f32 [17997376, 30797376)  N*128
//   q        : f32 [30797376, 37197376)  N*64
// total 37,197,376 * 4B = 148.8 MB

__global__ __launch_bounds__(256) void init_kernel(int4* __restrict__ counts_r,
                                                   int* __restrict__ ovfc) {
    int i = blockIdx.x * blockDim.x + threadIdx.x;
    if (i < (8 * RSTRIDE) / 4) counts_r[i] = make_int4(0, 0, 0, 0);
    if (i == 0) *ovfc = 0;
}

// x (fp32) -> xb (bf16, RTN)
__global__ __launch_bounds__(256) void prep_x_kernel(const float4* __restrict__ x4,
                                                     ushort4* __restrict__ xb4) {
    int i = blockIdx.x * blockDim.x + threadIdx.x;
    if (i >= N_NODES * 16) return;
    float4 v = x4[i];
    ushort4 o;
    o.x = f2bf(v.x); o.y = f2bf(v.y); o.z = f2bf(v.z); o.w = f2bf(v.w);
    xb4[i] = o;
}

// Pre-split weights into MFMA-fragment-ordered bf16 hi/lo.
// Bf layout: [(c*4+kc)*2 + term][lane][j]  (512 halfs per chunk)
//   element (k,n): c=n>>4, kc=k>>5, lane=((k>>3)&3)<<4 | (n&15), j=k&7
__global__ __launch_bounds__(256) void prep_b_kernel(
        const float* __restrict__ W1l, const float* __restrict__ W1r,
        const float* __restrict__ W2l, const float* __restrict__ W2r,
        short* __restrict__ Bf1, short* __restrict__ Bf2) {
    int idx = blockIdx.x * blockDim.x + threadIdx.x;
    if (idx >= 32768) return;
    int g = idx >> 14;
    int e = idx & 16383;
    int k = e >> 7;
    int n = e & 127;
    float v;
    if (g == 0) v = (k < 64) ? W1l[k * 128 + n] : W1r[(k - 64) * 128 + n];
    else        v = (n < 64) ? W2l[k * 64 + n]  : W2r[k * 64 + (n - 64)];
    unsigned u = __float_as_uint(v);
    unsigned hb = u >> 16;
    float vh = __uint_as_float(hb << 16);
    unsigned lb = __float_as_uint(v - vh) >> 16;
    int c = n >> 4, kc = k >> 5;
    int lane = (((k >> 3) & 3) << 4) | (n & 15);
    int j = k & 7;
    short* base = g ? Bf2 : Bf1;
    base[((c * 4 + kc) * 2 + 0) * 512 + lane * 8 + j] = (short)hb;
    base[((c * 4 + kc) * 2 + 1) * 512 + lane * 8 + j] = (short)lb;
}

// Phase 1: replicated histogram (8 replicas, replica by edge-block ~ XCD).
__global__ __launch_bounds__(256) void hist_kernel(
        const int* __restrict__ ei, int* __restrict__ counts_r,
        unsigned char* __restrict__ pos8) {
    int e = blockIdx.x * blockDim.x + threadIdx.x;
    if (e >= N_EDGES) return;
    int d = ei[N_EDGES + e];
    int r = (e >> 8) & 7;
    int p = atomicAdd(&counts_r[r * RSTRIDE + d], 1);
    pos8[e] = (unsigned char)(p < 255 ? p : 255);
}

// Phase 2: per-node prefix over the 8 replicas.
__global__ __launch_bounds__(256) void scan_kernel(
        const int* __restrict__ counts_r, int* __restrict__ bases_r,
        int* __restrict__ counts) {
    int d = blockIdx.x * blockDim.x + threadIdx.x;
    if (d >= N_NODES) return;
    int base = 0;
#pragma unroll
    for (int r = 0; r < 8; ++r) {
        bases_r[r * RSTRIDE + d] = base;
        base += counts_r[r * RSTRIDE + d];
    }
    counts[d] = base;
}

// Phase 3: atomic-free slot fill; overflow funnel for deg>64.
__global__ __launch_bounds__(256) void fill_kernel(
        const int* __restrict__ ei, const unsigned char* __restrict__ pos8,
        const int* __restrict__ bases_r, int* __restrict__ slots,
        int* __restrict__ ovfc, int* __restrict__ ovf) {
    int e = blockIdx.x * blockDim.x + threadIdx.x;
    if (e >= N_EDGES) return;
    int s = ei[e];
    int d = ei[N_EDGES + e];
    int r = (e >> 8) & 7;
    int p8 = pos8[e];
    int pos = bases_r[r * RSTRIDE + d] + p8;
    if (p8 < 255 && pos < DEG_CAP) {
        slots[d * DEG_CAP + pos] = s;
    } else {
        int o = atomicAdd(ovfc, 1);
        if (o < OVF_CAP) { ovf[o * 2] = s; ovf[o * 2 + 1] = d; }
    }
}

// One wave per node. Lane l: neighbor subgroup l>>4, features (l&15)*4..+3.
// One dwordx2 load covers 4 bf16 features of one neighbor; 4 subgroups ->
// 4 neighbor rows per load instruction. Butterfly-reduce across subgroups.
// Writes the MEAN (fp32).
__global__ __launch_bounds__(256) void gather_bf_kernel(
        const unsigned short* __restrict__ feat, const int* __restrict__ counts,
        const int* __restrict__ slots, float* __restrict__ agg) {
    int wid = blockIdx.x * 4 + (threadIdx.x >> 6);
    int l = threadIdx.x & 63;
    if (wid >= N_NODES) return;
    int deg = counts[wid];
    int dcap = min(deg, DEG_CAP);
    int ids = slots[wid * DEG_CAP + l];
    const int grp = l >> 4;
    const int fb = (l & 15) * 4;
    float s0 = 0.f, s1 = 0.f, s2 = 0.f, s3 = 0.f;
    int j = 0;
    for (; j + 8 <= dcap; j += 8) {   // grp<=3 -> both neighbors in-range
        int sA = __shfl(ids, j + grp);
        int sB = __shfl(ids, j + 4 + grp);
        uint2 uA = *(const uint2*)(feat + sA * 64 + fb);
        uint2 uB = *(const uint2*)(feat + sB * 64 + fb);
        s0 += bflo(uA.x) + bflo(uB.x);
        s1 += bfhi(uA.x) + bfhi(uB.x);
        s2 += bflo(uA.y) + bflo(uB.y);
        s3 += bfhi(uA.y) + bfhi(uB.y);
    }
    for (; j < dcap; j += 4) {
        int nb = j + grp;
        bool v = nb < dcap;
        int s = __shfl(ids, v ? nb : 0);
        uint2 u = *(const uint2*)(feat + s * 64 + fb);
        if (v) {
            s0 += bflo(u.x);
            s1 += bfhi(u.x);
            s2 += bflo(u.y);
            s3 += bfhi(u.y);
        }
    }
    // reduce across the 4 subgroups (lanes ^16, ^32)
    s0 += __shfl_xor(s0, 16); s0 += __shfl_xor(s0, 32);
    s1 += __shfl_xor(s1, 16); s1 += __shfl_xor(s1, 32);
    s2 += __shfl_xor(s2, 16); s2 += __shfl_xor(s2, 32);
    s3 += __shfl_xor(s3, 16); s3 += __shfl_xor(s3, 32);
    if (l < 16) {
        float inv = 1.0f / fmaxf((float)deg, 1.0f);
        *(float4*)&agg[wid * 64 + fb] =
            make_float4(s0 * inv, s1 * inv, s2 * inv, s3 * inv);
    }
}

// Layer-1 overflow: add x*inv into mean (fp32 x; overflow is ~never hit).
__global__ __launch_bounds__(64) void ovf_scatter_kernel(
        const float* __restrict__ feat, const int* __restrict__ ovf,
        const int* __restrict__ ovfc, const int* __restrict__ counts,
        float* __restrict__ agg) {
    int n = *ovfc;
    if (n > OVF_CAP) n = OVF_CAP;
    for (int idx = blockIdx.x; idx < n; idx += gridDim.x) {
        int s = ovf[idx * 2];
        int d = ovf[idx * 2 + 1];
        float inv = 1.0f / fmaxf((float)counts[d], 1.0f);
        atomicAdd(&agg[d * 64 + threadIdx.x], feat[s * 64 + threadIdx.x] * inv);
    }
}

// Layer 1 MFMA, B-stationary: h = relu( [mean|x] @ [W1l;W1r] + b1 )
// Block = 128 rows. Wave w owns col-tiles {2w, 2w+1}; its 16 B-frags (64
// VGPR) are loaded from L2 ONCE, then 8 row-tiles of A stream against them.
__global__ __launch_bounds__(256) void l1_mfma_kernel(
        const float* __restrict__ mean1, const float* __restrict__ x,
        const short* __restrict__ Bf1, const float* __restrict__ b1,
        float* __restrict__ h) {
    const int w = threadIdx.x >> 6;
    const int l = threadIdx.x & 63;
    const int lane15 = l & 15;
    const int quad = l >> 4;
    const int rowBase = blockIdx.x * 128;

    // resident B fragments: ci in {0,1} -> c = 2w+ci
    bf16x8 bh[2][4], bl[2][4];
#pragma unroll
    for (int ci = 0; ci < 2; ++ci) {
        const int c = 2 * w + ci;
#pragma unroll
        for (int kc = 0; kc < 4; ++kc) {
            const short* bp = Bf1 + ((c * 4 + kc) * 2) * 512 + l * 8;
            bh[ci][kc] = *(const bf16x8*)bp;
            bl[ci][kc] = *(const bf16x8*)(bp + 512);
        }
    }
    float bias[2];
#pragma unroll
    for (int ci = 0; ci < 2; ++ci) bias[ci] = b1[(2 * w + ci) * 16 + lane15];

#pragma unroll
    for (int rt = 0; rt < 8; ++rt) {
        const int row = rowBase + rt * 16 + lane15;
        const bool rv = row < N_NODES;

        bf16x8 ah[4], al[4];
#pragma unroll
        for (int kc = 0; kc < 4; ++kc) {
            float4 v0 = make_float4(0.f, 0.f, 0.f, 0.f);
            float4 v1 = make_float4(0.f, 0.f, 0.f, 0.f);
            if (rv) {
                const float* src = (kc < 2)
                    ? (mean1 + row * 64 + kc * 32 + quad * 8)
                    : (x     + row * 64 + (kc - 2) * 32 + quad * 8);
                v0 = *(const float4*)src;
                v1 = *(const float4*)(src + 4);
            }
            float f[8] = {v0.x, v0.y, v0.z, v0.w, v1.x, v1.y, v1.z, v1.w};
#pragma unroll
            for (int j = 0; j < 8; ++j) {
                unsigned u = __float_as_uint(f[j]);
                unsigned hb = u >> 16;
                float fh = __uint_as_float(hb << 16);
                unsigned lb = __float_as_uint(f[j] - fh) >> 16;
                ah[kc][j] = (short)hb;
                al[kc][j] = (short)lb;
            }
        }

        f32x4 acc[2] = {(f32x4){0.f, 0.f, 0.f, 0.f}, (f32x4){0.f, 0.f, 0.f, 0.f}};
#pragma unroll
        for (int kc = 0; kc < 4; ++kc) {
#pragma unroll
            for (int ci = 0; ci < 2; ++ci) {
                acc[ci] = __builtin_amdgcn_mfma_f32_16x16x32_bf16(ah[kc], bh[ci][kc], acc[ci], 0, 0, 0);
                acc[ci] = __builtin_amdgcn_mfma_f32_16x16x32_bf16(al[kc], bh[ci][kc], acc[ci], 0, 0, 0);
                acc[ci] = __builtin_amdgcn_mfma_f32_16x16x32_bf16(ah[kc], bl[ci][kc], acc[ci], 0, 0, 0);
            }
        }

        // C layout: col = c*16 + lane15, row = quad*4 + i
        const int rb = rowBase + rt * 16 + quad * 4;
#pragma unroll
        for (int ci = 0; ci < 2; ++ci) {
            const int col = (2 * w + ci) * 16 + lane15;
#pragma unroll
            for (int i = 0; i < 4; ++i) {
                int r = rb + i;
                if (r < N_NODES)
                    h[r * 128 + col] = fmaxf(acc[ci][i] + bias[ci], 0.f);
            }
        }
    }
}

// Layer 2 MFMA, B-stationary: p(bf16) = h @ W2l ; q(fp32) = h @ W2r + b2
// Waves 0-1 own c=0..3 (p half), waves 2-3 own c=4..7 (q half).
__global__ __launch_bounds__(256) void l2_mfma_kernel(
        const float* __restrict__ h, const short* __restrict__ Bf2,
        const float* __restrict__ b2,
        unsigned short* __restrict__ p_bf, float* __restrict__ q) {
    const int w = threadIdx.x >> 6;
    const int l = threadIdx.x & 63;
    const int lane15 = l & 15;
    const int quad = l >> 4;
    const int rowBase = blockIdx.x * 128;

    bf16x8 bh[2][4], bl[2][4];
#pragma unroll
    for (int ci = 0; ci < 2; ++ci) {
        const int c = 2 * w + ci;
#pragma unroll
        for (int kc = 0; kc < 4; ++kc) {
            const short* bp = Bf2 + ((c * 4 + kc) * 2) * 512 + l * 8;
            bh[ci][kc] = *(const bf16x8*)bp;
            bl[ci][kc] = *(const bf16x8*)(bp + 512);
        }
    }
    float bias[2];
#pragma unroll
    for (int ci = 0; ci < 2; ++ci) {
        const int c = 2 * w + ci;
        bias[ci] = (c >= 4) ? b2[(c - 4) * 16 + lane15] : 0.f;
    }

#pragma unroll
    for (int rt = 0; rt < 8; ++rt) {
        const int row = rowBase + rt * 16 + lane15;
        const bool rv = row < N_NODES;

        bf16x8 ah[4], al[4];
#pragma unroll
        for (int kc = 0; kc < 4; ++kc) {
            float4 v0 = make_float4(0.f, 0.f, 0.f, 0.f);
            float4 v1 = make_float4(0.f, 0.f, 0.f, 0.f);
            if (rv) {
                const float* src = h + row * 128 + kc * 32 + quad * 8;
                v0 = *(const float4*)src;
                v1 = *(const float4*)(src + 4);
            }
            float f[8] = {v0.x, v0.y, v0.z, v0.w, v1.x, v1.y, v1.z, v1.w};
#pragma unroll
            for (int j = 0; j < 8; ++j) {
                unsigned u = __float_as_uint(f[j]);
                unsigned hb = u >> 16;
                float fh = __uint_as_float(hb << 16);
                unsigned lb = __float_as_uint(f[j] - fh) >> 16;
                ah[kc][j] = (short)hb;
                al[kc][j] = (short)lb;
            }
        }

        f32x4 acc[2] = {(f32x4){0.f, 0.f, 0.f, 0.f}, (f32x4){0.f, 0.f, 0.f, 0.f}};
#pragma unroll
        for (int kc = 0; kc < 4; ++kc) {
#pragma unroll
            for (int ci = 0; ci < 2; ++ci) {
                acc[ci] = __builtin_amdgcn_mfma_f32_16x16x32_bf16(ah[kc], bh[ci][kc], acc[ci], 0, 0, 0);
                acc[ci] = __builtin_amdgcn_mfma_f32_16x16x32_bf16(al[kc], bh[ci][kc], acc[ci], 0, 0, 0);
                acc[ci] = __builtin_amdgcn_mfma_f32_16x16x32_bf16(ah[kc], bl[ci][kc], acc[ci], 0, 0, 0);
            }
        }

        const int rb = rowBase + rt * 16 + quad * 4;
#pragma unroll
        for (int ci = 0; ci < 2; ++ci) {
            const int c = 2 * w + ci;
            if (c < 4) {
#pragma unroll
                for (int i = 0; i < 4; ++i) {
                    int r = rb + i;
                    if (r < N_NODES)
                        p_bf[r * 64 + c * 16 + lane15] = f2bf(acc[ci][i]);
                }
            } else {
#pragma unroll
                for (int i = 0; i < 4; ++i) {
                    int r = rb + i;
                    if (r < N_NODES)
                        q[r * 64 + (c - 4) * 16 + lane15] = acc[ci][i] + bias[ci];
                }
            }
        }
    }
}

// Fused layer-2 aggregation + epilogue: out = mean(p_bf[nbrs]) + q
// Same 4-neighbors-per-load structure as gather_bf_kernel.
__global__ __launch_bounds__(256) void gather_final_kernel(
        const unsigned short* __restrict__ p, const int* __restrict__ counts,
        const int* __restrict__ slots, const float* __restrict__ q,
        float* __restrict__ out) {
    int wid = blockIdx.x * 4 + (threadIdx.x >> 6);
    int l = threadIdx.x & 63;
    if (wid >= N_NODES) return;
    int deg = counts[wid];
    int dcap = min(deg, DEG_CAP);
    int ids = slots[wid * DEG_CAP + l];
    const int grp = l >> 4;
    const int fb = (l & 15) * 4;
    float s0 = 0.f, s1 = 0.f, s2 = 0.f, s3 = 0.f;
    int j = 0;
    for (; j + 8 <= dcap; j += 8) {
        int sA = __shfl(ids, j + grp);
        int sB = __shfl(ids, j + 4 + grp);
        uint2 uA = *(const uint2*)(p + sA * 64 + fb);
        uint2 uB = *(const uint2*)(p + sB * 64 + fb);
        s0 += bflo(uA.x) + bflo(uB.x);
        s1 += bfhi(uA.x) + bfhi(uB.x);
        s2 += bflo(uA.y) + bflo(uB.y);
        s3 += bfhi(uA.y) + bfhi(uB.y);
    }
    for (; j < dcap; j += 4) {
        int nb = j + grp;
        bool v = nb < dcap;
        int s = __shfl(ids, v ? nb : 0);
        uint2 u = *(const uint2*)(p + s * 64 + fb);
        if (v) {
            s0 += bflo(u.x);
            s1 += bfhi(u.x);
            s2 += bflo(u.y);
            s3 += bfhi(u.y);
        }
    }
    s0 += __shfl_xor(s0, 16); s0 += __shfl_xor(s0, 32);
    s1 += __shfl_xor(s1, 16); s1 += __shfl_xor(s1, 32);
    s2 += __shfl_xor(s2, 16); s2 += __shfl_xor(s2, 32);
    s3 += __shfl_xor(s3, 16); s3 += __shfl_xor(s3, 32);
    if (l < 16) {
        float inv = 1.0f / fmaxf((float)deg, 1.0f);
        float4 qv = *(const float4*)&q[wid * 64 + fb];
        *(float4*)&out[wid * 64 + fb] =
            make_float4(s0 * inv + qv.x, s1 * inv + qv.y,
                        s2 * inv + qv.z, s3 * inv + qv.w);
    }
}

// Layer-2 overflow fix-up (additive).
__global__ __launch_bounds__(64) void ovf_fixup_kernel(
        const unsigned short* __restrict__ p, const int* __restrict__ ovf,
        const int* __restrict__ ovfc, const int* __restrict__ counts,
        float* __restrict__ out) {
    int n = *ovfc;
    if (n > OVF_CAP) n = OVF_CAP;
    for (int idx = blockIdx.x; idx < n; idx += gridDim.x) {
        int s = ovf[idx * 2];
        int d = ovf[idx * 2 + 1];
        float inv = 1.0f / fmaxf((float)counts[d], 1.0f);
        atomicAdd(&out[d * 64 + threadIdx.x],
                  bf2f(p[s * 64 + threadIdx.x]) * inv);
    }
}

extern "C" void kernel_launch(void* const* d_in, const int* in_sizes, int n_in,
                              void* d_out, int out_size, void* d_ws, size_t ws_size,
                              hipStream_t stream) {
    const float* x   = (const float*)d_in[0];
    const float* W1l = (const float*)d_in[1];
    const float* W1r = (const float*)d_in[2];
    const float* b1  = (const float*)d_in[3];
    const float* W2l = (const float*)d_in[4];
    const float* W2r = (const float*)d_in[5];
    const float* b2  = (const float*)d_in[6];
    const int*   ei  = (const int*)d_in[7];

    int*   wsi      = (int*)d_ws;
    float* wsf      = (float*)d_ws;
    int*   counts_r = wsi;
    int*   bases_r  = wsi + 802816;
    int*   counts   = wsi + 1605632;
    unsigned char* pos8 = (unsigned char*)(wsi + 1705984);
    int*   ovfc     = wsi + 1956352;
    int*   ovf      = wsi + 1956416;
    short* Bf1      = (short*)(wsi + 1964608);
    short* Bf2      = (short*)(wsi + 1980992);
    int*   slots    = wsi + 1997376;
    unsigned short* xb = (unsigned short*)(wsi + 8397376);   // 3.2M units
    float* mean1    = wsf + 11597376;
    unsigned short* p_bf = (unsigned short*)(wsf + 11597376);  // reuse after l1
    float* h        = wsf + 17997376;
    float* q        = wsf + 30797376;
    float* out      = (float*)d_out;

    init_kernel<<<(8 * RSTRIDE / 4 + 255) / 256, 256, 0, stream>>>(
        (int4*)counts_r, ovfc);
    prep_b_kernel<<<128, 256, 0, stream>>>(W1l, W1r, W2l, W2r, Bf1, Bf2);
    prep_x_kernel<<<(N_NODES * 16 + 255) / 256, 256, 0, stream>>>(
        (const float4*)x, (ushort4*)xb);
    hist_kernel<<<(N_EDGES + 255) / 256, 256, 0, stream>>>(ei, counts_r, pos8);
    scan_kernel<<<(N_NODES + 255) / 256, 256, 0, stream>>>(counts_r, bases_r, counts);
    fill_kernel<<<(N_EDGES + 255) / 256, 256, 0, stream>>>(
        ei, pos8, bases_r, slots, ovfc, ovf);

    // layer-1 aggregation -> mean (bf16 rows), + overflow
    gather_bf_kernel<<<(N_NODES + 3) / 4, 256, 0, stream>>>(xb, counts, slots, mean1);
    ovf_scatter_kernel<<<64, 64, 0, stream>>>(x, ovf, ovfc, counts, mean1);

    // h = relu([mean|x] @ [W1l;W1r] + b1)
    l1_mfma_kernel<<<(N_NODES + 127) / 128, 256, 0, stream>>>(
        mean1, x, Bf1, b1, h);
    // p(bf16) = h @ W2l ; q = h @ W2r + b2   (p_bf overwrites mean1)
    l2_mfma_kernel<<<(N_NODES + 127) / 128, 256, 0, stream>>>(h, Bf2, b2, p_bf, q);

    // fused layer-2 aggregation + epilogue, then overflow fix-up
    gather_final_kernel<<<(N_NODES + 3) / 4, 256, 0, stream>>>(
        p_bf, counts, slots, q, out);
    ovf_fixup_kernel<<<64, 64, 0, stream>>>(p_bf, ovf, ovfc, counts, out);
}

// Round 9
// 284.071 us; speedup vs baseline: 2.4391x; 1.0116x over previous
//
#include <hip/hip_runtime.h>

#define N_NODES 100000
#define N_EDGES 1000000
#define DEG_CAP 64
#define OVF_CAP 4096
#define RSTRIDE 100352   // N_NODES rounded up to 512

typedef __attribute__((ext_vector_type(8))) short bf16x8;
typedef __attribute__((ext_vector_type(4))) float f32x4;

__device__ __forceinline__ unsigned short f2bf(float f) {
    unsigned u = __float_as_uint(f);
    return (unsigned short)((u + 0x7FFF + ((u >> 16) & 1)) >> 16);
}
__device__ __forceinline__ float bf2f(unsigned short b) {
    return __uint_as_float(((unsigned)b) << 16);
}
__device__ __forceinline__ float bflo(unsigned u) {   // low bf16 of a dword
    return __uint_as_float(u << 16);
}
__device__ __forceinline__ float bfhi(unsigned u) {   // high bf16 of a dword
    return __uint_as_float(u & 0xffff0000u);
}

// ws layout (4B units):
//   counts_r : int [0,        802816)     8 replicas x RSTRIDE
//   bases_r  : int [802816,  1605632)
//   counts   : int [1605632, 1705984)
//   pos16    : u16 [1705984, 2205984)     1M u16 = (replica<<13)|pos
//   ovfc     : int [2205984]
//   ovf      : int [2206048, 2214240)
//   Bf1      : s16 [2214240, 2230624)     32768 halfs (frag-ordered hi/lo)
//   Bf2      : s16 [2230624, 2247008)
//   slots    : int [2247008, 8647008)     N*64
//   xb       : u16 [8647008, 11847008)    N*64 bf16
//   mean1    : f32 [11847008, 18247008)   N*64; reused as p_bf after l1
//   h        : f32 [18247008, 31047008)   N*128
//   q        : f32 [31047008, 37447008)   N*64
// total 37,447,008 * 4B = 149.8 MB

// Merged init + weight-split + x->bf16 (grid-stride style, one launch).
__global__ __launch_bounds__(256) void prep_kernel(
        const float4* __restrict__ x4, ushort4* __restrict__ xb4,
        const float* __restrict__ W1l, const float* __restrict__ W1r,
        const float* __restrict__ W2l, const float* __restrict__ W2r,
        short* __restrict__ Bf1, short* __restrict__ Bf2,
        int4* __restrict__ counts_r4, int* __restrict__ ovfc) {
    int i = blockIdx.x * blockDim.x + threadIdx.x;
    if (i < (8 * RSTRIDE) / 4) counts_r4[i] = make_int4(0, 0, 0, 0);
    if (i == 0) *ovfc = 0;
    if (i < 32768) {
        int g = i >> 14;
        int e = i & 16383;
        int k = e >> 7;
        int n = e & 127;
        float v;
        if (g == 0) v = (k < 64) ? W1l[k * 128 + n] : W1r[(k - 64) * 128 + n];
        else        v = (n < 64) ? W2l[k * 64 + n]  : W2r[k * 64 + (n - 64)];
        unsigned u = __float_as_uint(v);
        unsigned hb = u >> 16;
        float vh = __uint_as_float(hb << 16);
        unsigned lb = __float_as_uint(v - vh) >> 16;
        int c = n >> 4, kc = k >> 5;
        int lane = (((k >> 3) & 3) << 4) | (n & 15);
        int j = k & 7;
        short* base = g ? Bf2 : Bf1;
        base[((c * 4 + kc) * 2 + 0) * 512 + lane * 8 + j] = (short)hb;
        base[((c * 4 + kc) * 2 + 1) * 512 + lane * 8 + j] = (short)lb;
    }
    if (i < N_NODES * 16) {
        float4 v = x4[i];
        ushort4 o;
        o.x = f2bf(v.x); o.y = f2bf(v.y); o.z = f2bf(v.z); o.w = f2bf(v.w);
        xb4[i] = o;
    }
}

// Phase 1: replicated histogram. Replica = ACTUAL XCD id (s_getreg), so
// replica-r counter lines are touched only by XCD r -> XCD-local L2 atomics,
// no cross-XCD line migration. Stash (replica,pos) per edge as u16.
__global__ __launch_bounds__(256) void hist_kernel(
        const int* __restrict__ ei, int* __restrict__ counts_r,
        unsigned short* __restrict__ pos16) {
    int e = blockIdx.x * blockDim.x + threadIdx.x;
    if (e >= N_EDGES) return;
    unsigned xcc;
    asm volatile("s_getreg_b32 %0, hwreg(HW_REG_XCC_ID)" : "=s"(xcc));
    int r = xcc & 7;
    int d = ei[N_EDGES + e];
    int p = atomicAdd(&counts_r[r * RSTRIDE + d], 1);
    if (p > 8191) p = 8191;
    pos16[e] = (unsigned short)((r << 13) | p);
}

// Phase 2: per-node prefix over the 8 replicas.
__global__ __launch_bounds__(256) void scan_kernel(
        const int* __restrict__ counts_r, int* __restrict__ bases_r,
        int* __restrict__ counts) {
    int d = blockIdx.x * blockDim.x + threadIdx.x;
    if (d >= N_NODES) return;
    int base = 0;
#pragma unroll
    for (int r = 0; r < 8; ++r) {
        bases_r[r * RSTRIDE + d] = base;
        base += counts_r[r * RSTRIDE + d];
    }
    counts[d] = base;
}

// Phase 3: atomic-free slot fill; overflow funnel for pos>=64 (or capped p).
__global__ __launch_bounds__(256) void fill_kernel(
        const int* __restrict__ ei, const unsigned short* __restrict__ pos16,
        const int* __restrict__ bases_r, int* __restrict__ slots,
        int* __restrict__ ovfc, int* __restrict__ ovf) {
    int e = blockIdx.x * blockDim.x + threadIdx.x;
    if (e >= N_EDGES) return;
    int s = ei[e];
    int d = ei[N_EDGES + e];
    unsigned pk = pos16[e];
    int r = pk >> 13;
    int p = pk & 8191;
    int pos = bases_r[r * RSTRIDE + d] + p;
    if (p < 8191 && pos < DEG_CAP) {
        slots[d * DEG_CAP + pos] = s;
    } else {
        int o = atomicAdd(ovfc, 1);
        if (o < OVF_CAP) { ovf[o * 2] = s; ovf[o * 2 + 1] = d; }
    }
}

// One wave per node. Lane l: neighbor subgroup l>>4, features (l&15)*4..+3.
// One dwordx2 load covers 4 bf16 features of one neighbor; 4 subgroups ->
// 4 neighbor rows per load instruction. Butterfly-reduce across subgroups.
// Writes the MEAN (fp32).
__global__ __launch_bounds__(256) void gather_bf_kernel(
        const unsigned short* __restrict__ feat, const int* __restrict__ counts,
        const int* __restrict__ slots, float* __restrict__ agg) {
    int wid = blockIdx.x * 4 + (threadIdx.x >> 6);
    int l = threadIdx.x & 63;
    if (wid >= N_NODES) return;
    int deg = counts[wid];
    int dcap = min(deg, DEG_CAP);
    int ids = slots[wid * DEG_CAP + l];
    const int grp = l >> 4;
    const int fb = (l & 15) * 4;
    float s0 = 0.f, s1 = 0.f, s2 = 0.f, s3 = 0.f;
    int j = 0;
    for (; j + 8 <= dcap; j += 8) {   // grp<=3 -> both neighbors in-range
        int sA = __shfl(ids, j + grp);
        int sB = __shfl(ids, j + 4 + grp);
        uint2 uA = *(const uint2*)(feat + sA * 64 + fb);
        uint2 uB = *(const uint2*)(feat + sB * 64 + fb);
        s0 += bflo(uA.x) + bflo(uB.x);
        s1 += bfhi(uA.x) + bfhi(uB.x);
        s2 += bflo(uA.y) + bflo(uB.y);
        s3 += bfhi(uA.y) + bfhi(uB.y);
    }
    for (; j < dcap; j += 4) {
        int nb = j + grp;
        bool v = nb < dcap;
        int s = __shfl(ids, v ? nb : 0);
        uint2 u = *(const uint2*)(feat + s * 64 + fb);
        if (v) {
            s0 += bflo(u.x);
            s1 += bfhi(u.x);
            s2 += bflo(u.y);
            s3 += bfhi(u.y);
        }
    }
    // reduce across the 4 subgroups (lanes ^16, ^32)
    s0 += __shfl_xor(s0, 16); s0 += __shfl_xor(s0, 32);
    s1 += __shfl_xor(s1, 16); s1 += __shfl_xor(s1, 32);
    s2 += __shfl_xor(s2, 16); s2 += __shfl_xor(s2, 32);
    s3 += __shfl_xor(s3, 16); s3 += __shfl_xor(s3, 32);
    if (l < 16) {
        float inv = 1.0f / fmaxf((float)deg, 1.0f);
        *(float4*)&agg[wid * 64 + fb] =
            make_float4(s0 * inv, s1 * inv, s2 * inv, s3 * inv);
    }
}

// Layer-1 overflow: add x*inv into mean (fp32 x; overflow is ~never hit).
__global__ __launch_bounds__(64) void ovf_scatter_kernel(
        const float* __restrict__ feat, const int* __restrict__ ovf,
        const int* __restrict__ ovfc, const int* __restrict__ counts,
        float* __restrict__ agg) {
    int n = *ovfc;
    if (n > OVF_CAP) n = OVF_CAP;
    for (int idx = blockIdx.x; idx < n; idx += gridDim.x) {
        int s = ovf[idx * 2];
        int d = ovf[idx * 2 + 1];
        float inv = 1.0f / fmaxf((float)counts[d], 1.0f);
        atomicAdd(&agg[d * 64 + threadIdx.x], feat[s * 64 + threadIdx.x] * inv);
    }
}

// Layer 1 MFMA, B-stationary: h = relu( [mean|x] @ [W1l;W1r] + b1 )
// Block = 128 rows. Wave w owns col-tiles {2w, 2w+1}; its 16 B-frags (64
// VGPR) are loaded from L2 ONCE, then 8 row-tiles of A stream against them.
__global__ __launch_bounds__(256) void l1_mfma_kernel(
        const float* __restrict__ mean1, const float* __restrict__ x,
        const short* __restrict__ Bf1, const float* __restrict__ b1,
        float* __restrict__ h) {
    const int w = threadIdx.x >> 6;
    const int l = threadIdx.x & 63;
    const int lane15 = l & 15;
    const int quad = l >> 4;
    const int rowBase = blockIdx.x * 128;

    // resident B fragments: ci in {0,1} -> c = 2w+ci
    bf16x8 bh[2][4], bl[2][4];
#pragma unroll
    for (int ci = 0; ci < 2; ++ci) {
        const int c = 2 * w + ci;
#pragma unroll
        for (int kc = 0; kc < 4; ++kc) {
            const short* bp = Bf1 + ((c * 4 + kc) * 2) * 512 + l * 8;
            bh[ci][kc] = *(const bf16x8*)bp;
            bl[ci][kc] = *(const bf16x8*)(bp + 512);
        }
    }
    float bias[2];
#pragma unroll
    for (int ci = 0; ci < 2; ++ci) bias[ci] = b1[(2 * w + ci) * 16 + lane15];

#pragma unroll
    for (int rt = 0; rt < 8; ++rt) {
        const int row = rowBase + rt * 16 + lane15;
        const bool rv = row < N_NODES;

        bf16x8 ah[4], al[4];
#pragma unroll
        for (int kc = 0; kc < 4; ++kc) {
            float4 v0 = make_float4(0.f, 0.f, 0.f, 0.f);
            float4 v1 = make_float4(0.f, 0.f, 0.f, 0.f);
            if (rv) {
                const float* src = (kc < 2)
                    ? (mean1 + row * 64 + kc * 32 + quad * 8)
                    : (x     + row * 64 + (kc - 2) * 32 + quad * 8);
                v0 = *(const float4*)src;
                v1 = *(const float4*)(src + 4);
            }
            float f[8] = {v0.x, v0.y, v0.z, v0.w, v1.x, v1.y, v1.z, v1.w};
#pragma unroll
            for (int j = 0; j < 8; ++j) {
                unsigned u = __float_as_uint(f[j]);
                unsigned hb = u >> 16;
                float fh = __uint_as_float(hb << 16);
                unsigned lb = __float_as_uint(f[j] - fh) >> 16;
                ah[kc][j] = (short)hb;
                al[kc][j] = (short)lb;
            }
        }

        f32x4 acc[2] = {(f32x4){0.f, 0.f, 0.f, 0.f}, (f32x4){0.f, 0.f, 0.f, 0.f}};
#pragma unroll
        for (int kc = 0; kc < 4; ++kc) {
#pragma unroll
            for (int ci = 0; ci < 2; ++ci) {
                acc[ci] = __builtin_amdgcn_mfma_f32_16x16x32_bf16(ah[kc], bh[ci][kc], acc[ci], 0, 0, 0);
                acc[ci] = __builtin_amdgcn_mfma_f32_16x16x32_bf16(al[kc], bh[ci][kc], acc[ci], 0, 0, 0);
                acc[ci] = __builtin_amdgcn_mfma_f32_16x16x32_bf16(ah[kc], bl[ci][kc], acc[ci], 0, 0, 0);
            }
        }

        // C layout: col = c*16 + lane15, row = quad*4 + i
        const int rb = rowBase + rt * 16 + quad * 4;
#pragma unroll
        for (int ci = 0; ci < 2; ++ci) {
            const int col = (2 * w + ci) * 16 + lane15;
#pragma unroll
            for (int i = 0; i < 4; ++i) {
                int r = rb + i;
                if (r < N_NODES)
                    h[r * 128 + col] = fmaxf(acc[ci][i] + bias[ci], 0.f);
            }
        }
    }
}

// Layer 2 MFMA, B-stationary: p(bf16) = h @ W2l ; q(fp32) = h @ W2r + b2
// Waves 0-1 own c=0..3 (p half), waves 2-3 own c=4..7 (q half).
__global__ __launch_bounds__(256) void l2_mfma_kernel(
        const float* __restrict__ h, const short* __restrict__ Bf2,
        const float* __restrict__ b2,
        unsigned short* __restrict__ p_bf, float* __restrict__ q) {
    const int w = threadIdx.x >> 6;
    const int l = threadIdx.x & 63;
    const int lane15 = l & 15;
    const int quad = l >> 4;
    const int rowBase = blockIdx.x * 128;

    bf16x8 bh[2][4], bl[2][4];
#pragma unroll
    for (int ci = 0; ci < 2; ++ci) {
        const int c = 2 * w + ci;
#pragma unroll
        for (int kc = 0; kc < 4; ++kc) {
            const short* bp = Bf2 + ((c * 4 + kc) * 2) * 512 + l * 8;
            bh[ci][kc] = *(const bf16x8*)bp;
            bl[ci][kc] = *(const bf16x8*)(bp + 512);
        }
    }
    float bias[2];
#pragma unroll
    for (int ci = 0; ci < 2; ++ci) {
        const int c = 2 * w + ci;
        bias[ci] = (c >= 4) ? b2[(c - 4) * 16 + lane15] : 0.f;
    }

#pragma unroll
    for (int rt = 0; rt < 8; ++rt) {
        const int row = rowBase + rt * 16 + lane15;
        const bool rv = row < N_NODES;

        bf16x8 ah[4], al[4];
#pragma unroll
        for (int kc = 0; kc < 4; ++kc) {
            float4 v0 = make_float4(0.f, 0.f, 0.f, 0.f);
            float4 v1 = make_float4(0.f, 0.f, 0.f, 0.f);
            if (rv) {
                const float* src = h + row * 128 + kc * 32 + quad * 8;
                v0 = *(const float4*)src;
                v1 = *(const float4*)(src + 4);
            }
            float f[8] = {v0.x, v0.y, v0.z, v0.w, v1.x, v1.y, v1.z, v1.w};
#pragma unroll
            for (int j = 0; j < 8; ++j) {
                unsigned u = __float_as_uint(f[j]);
                unsigned hb = u >> 16;
                float fh = __uint_as_float(hb << 16);
                unsigned lb = __float_as_uint(f[j] - fh) >> 16;
                ah[kc][j] = (short)hb;
                al[kc][j] = (short)lb;
            }
        }

        f32x4 acc[2] = {(f32x4){0.f, 0.f, 0.f, 0.f}, (f32x4){0.f, 0.f, 0.f, 0.f}};
#pragma unroll
        for (int kc = 0; kc < 4; ++kc) {
#pragma unroll
            for (int ci = 0; ci < 2; ++ci) {
                acc[ci] = __builtin_amdgcn_mfma_f32_16x16x32_bf16(ah[kc], bh[ci][kc], acc[ci], 0, 0, 0);
                acc[ci] = __builtin_amdgcn_mfma_f32_16x16x32_bf16(al[kc], bh[ci][kc], acc[ci], 0, 0, 0);
                acc[ci] = __builtin_amdgcn_mfma_f32_16x16x32_bf16(ah[kc], bl[ci][kc], acc[ci], 0, 0, 0);
            }
        }

        const int rb = rowBase + rt * 16 + quad * 4;
#pragma unroll
        for (int ci = 0; ci < 2; ++ci) {
            const int c = 2 * w + ci;
            if (c < 4) {
#pragma unroll
                for (int i = 0; i < 4; ++i) {
                    int r = rb + i;
                    if (r < N_NODES)
                        p_bf[r * 64 + c * 16 + lane15] = f2bf(acc[ci][i]);
                }
            } else {
#pragma unroll
                for (int i = 0; i < 4; ++i) {
                    int r = rb + i;
                    if (r < N_NODES)
                        q[r * 64 + (c - 4) * 16 + lane15] = acc[ci][i] + bias[ci];
                }
            }
        }
    }
}

// Fused layer-2 aggregation + epilogue: out = mean(p_bf[nbrs]) + q
// Same 4-neighbors-per-load structure as gather_bf_kernel.
__global__ __launch_bounds__(256) void gather_final_kernel(
        const unsigned short* __restrict__ p, const int* __restrict__ counts,
        const int* __restrict__ slots, const float* __restrict__ q,
        float* __restrict__ out) {
    int wid = blockIdx.x * 4 + (threadIdx.x >> 6);
    int l = threadIdx.x & 63;
    if (wid >= N_NODES) return;
    int deg = counts[wid];
    int dcap = min(deg, DEG_CAP);
    int ids = slots[wid * DEG_CAP + l];
    const int grp = l >> 4;
    const int fb = (l & 15) * 4;
    float s0 = 0.f, s1 = 0.f, s2 = 0.f, s3 = 0.f;
    int j = 0;
    for (; j + 8 <= dcap; j += 8) {
        int sA = __shfl(ids, j + grp);
        int sB = __shfl(ids, j + 4 + grp);
        uint2 uA = *(const uint2*)(p + sA * 64 + fb);
        uint2 uB = *(const uint2*)(p + sB * 64 + fb);
        s0 += bflo(uA.x) + bflo(uB.x);
        s1 += bfhi(uA.x) + bfhi(uB.x);
        s2 += bflo(uA.y) + bflo(uB.y);
        s3 += bfhi(uA.y) + bfhi(uB.y);
    }
    for (; j < dcap; j += 4) {
        int nb = j + grp;
        bool v = nb < dcap;
        int s = __shfl(ids, v ? nb : 0);
        uint2 u = *(const uint2*)(p + s * 64 + fb);
        if (v) {
            s0 += bflo(u.x);
            s1 += bfhi(u.x);
            s2 += bflo(u.y);
            s3 += bfhi(u.y);
        }
    }
    s0 += __shfl_xor(s0, 16); s0 += __shfl_xor(s0, 32);
    s1 += __shfl_xor(s1, 16); s1 += __shfl_xor(s1, 32);
    s2 += __shfl_xor(s2, 16); s2 += __shfl_xor(s2, 32);
    s3 += __shfl_xor(s3, 16); s3 += __shfl_xor(s3, 32);
    if (l < 16) {
        float inv = 1.0f / fmaxf((float)deg, 1.0f);
        float4 qv = *(const float4*)&q[wid * 64 + fb];
        *(float4*)&out[wid * 64 + fb] =
            make_float4(s0 * inv + qv.x, s1 * inv + qv.y,
                        s2 * inv + qv.z, s3 * inv + qv.w);
    }
}

// Layer-2 overflow fix-up (additive).
__global__ __launch_bounds__(64) void ovf_fixup_kernel(
        const unsigned short* __restrict__ p, const int* __restrict__ ovf,
        const int* __restrict__ ovfc, const int* __restrict__ counts,
        float* __restrict__ out) {
    int n = *ovfc;
    if (n > OVF_CAP) n = OVF_CAP;
    for (int idx = blockIdx.x; idx < n; idx += gridDim.x) {
        int s = ovf[idx * 2];
        int d = ovf[idx * 2 + 1];
        float inv = 1.0f / fmaxf((float)counts[d], 1.0f);
        atomicAdd(&out[d * 64 + threadIdx.x],
                  bf2f(p[s * 64 + threadIdx.x]) * inv);
    }
}

extern "C" void kernel_launch(void* const* d_in, const int* in_sizes, int n_in,
                              void* d_out, int out_size, void* d_ws, size_t ws_size,
                              hipStream_t stream) {
    const float* x   = (const float*)d_in[0];
    const float* W1l = (const float*)d_in[1];
    const float* W1r = (const float*)d_in[2];
    const float* b1  = (const float*)d_in[3];
    const float* W2l = (const float*)d_in[4];
    const float* W2r = (const float*)d_in[5];
    const float* b2  = (const float*)d_in[6];
    const int*   ei  = (const int*)d_in[7];

    int*   wsi      = (int*)d_ws;
    float* wsf      = (float*)d_ws;
    int*   counts_r = wsi;
    int*   bases_r  = wsi + 802816;
    int*   counts   = wsi + 1605632;
    unsigned short* pos16 = (unsigned short*)(wsi + 1705984);
    int*   ovfc     = wsi + 2205984;
    int*   ovf      = wsi + 2206048;
    short* Bf1      = (short*)(wsi + 2214240);
    short* Bf2      = (short*)(wsi + 2230624);
    int*   slots    = wsi + 2247008;
    unsigned short* xb = (unsigned short*)(wsi + 8647008);
    float* mean1    = wsf + 11847008;
    unsigned short* p_bf = (unsigned short*)(wsf + 11847008);  // reuse after l1
    float* h        = wsf + 18247008;
    float* q        = wsf + 31047008;
    float* out      = (float*)d_out;

    // merged init + prep (covers max(200704, 32768, 1.6M) indices)
    prep_kernel<<<(N_NODES * 16 + 255) / 256, 256, 0, stream>>>(
        (const float4*)x, (ushort4*)xb, W1l, W1r, W2l, W2r, Bf1, Bf2,
        (int4*)counts_r, ovfc);
    hist_kernel<<<(N_EDGES + 255) / 256, 256, 0, stream>>>(ei, counts_r, pos16);
    scan_kernel<<<(N_NODES + 255) / 256, 256, 0, stream>>>(counts_r, bases_r, counts);
    fill_kernel<<<(N_EDGES + 255) / 256, 256, 0, stream>>>(
        ei, pos16, bases_r, slots, ovfc, ovf);

    // layer-1 aggregation -> mean (bf16 rows), + overflow
    gather_bf_kernel<<<(N_NODES + 3) / 4, 256, 0, stream>>>(xb, counts, slots, mean1);
    ovf_scatter_kernel<<<64, 64, 0, stream>>>(x, ovf, ovfc, counts, mean1);

    // h = relu([mean|x] @ [W1l;W1r] + b1)
    l1_mfma_kernel<<<(N_NODES + 127) / 128, 256, 0, stream>>>(
        mean1, x, Bf1, b1, h);
    // p(bf16) = h @ W2l ; q = h @ W2r + b2   (p_bf overwrites mean1)
    l2_mfma_kernel<<<(N_NODES + 127) / 128, 256, 0, stream>>>(h, Bf2, b2, p_bf, q);

    // fused layer-2 aggregation + epilogue, then overflow fix-up
    gather_final_kernel<<<(N_NODES + 3) / 4, 256, 0, stream>>>(
        p_bf, counts, slots, q, out);
    ovf_fixup_kernel<<<64, 64, 0, stream>>>(p_bf, ovf, ovfc, counts, out);
}